// Round 8
// baseline (1796.372 us; speedup 1.0000x reference)
//
#include <hip/hip_runtime.h>
#include <math.h>

typedef __attribute__((ext_vector_type(8))) short short8;
typedef __attribute__((ext_vector_type(4))) float f32x4;
typedef __attribute__((ext_vector_type(4))) unsigned short ushort4v;
typedef __attribute__((ext_vector_type(8))) unsigned short ushort8v;

#define DEV static __device__ __forceinline__

namespace {

constexpr int kB = 2;
constexpr int kTraw = 8000;
constexpr int kF = 40;
constexpr int kT1 = 3999;
constexpr int kC1 = 512;
constexpr int kT = 1999;
constexpr int kD = 768;
constexpr int kM = kB * kT;    // 3998
constexpr int kM1 = kB * kT1;  // 7998
constexpr int kH = 12;
constexpr int kDH = 64;
constexpr int kL = 8;
constexpr int kV = 8000;
constexpr int kPK = 95;
constexpr int kPKp = 96;
constexpr int kPG = 16;
constexpr int kCG = 48;
constexpr int kTP = 2048;
constexpr int kNCH = 2;        // kv chunks (16 tiles each)
constexpr int kCT = 32 / kNCH; // tiles per chunk
constexpr float kWIN = 8.0f;   // ALiBi window threshold (nats)

DEV unsigned short f2bf(float x){
  union{unsigned int i; float f;} v; v.f = x;
  unsigned int r = v.i + 0x7FFFu + ((v.i >> 16) & 1u);
  return (unsigned short)(r >> 16);
}
DEV float bf2f(unsigned short u){
  union{unsigned int i; float f;} v; v.i = ((unsigned int)u) << 16; return v.f;
}
DEV float gelu_f(float x){
  return 0.5f * x * (1.0f + tanhf(0.7978845608028654f * (x + 0.044715f * x * x * x)));
}
DEV void gl2lds16(const unsigned short* g, unsigned short* l){
  __builtin_amdgcn_global_load_lds(
      (const __attribute__((address_space(1))) unsigned int*)(g),
      (__attribute__((address_space(3))) unsigned int*)(l), 16, 0, 0);
}
DEV void xcd_map(int bid, int Mtiles, int Ntiles, int& tm, int& tn){
  const int nwg = Mtiles * Ntiles;
  const int qq = nwg >> 3, rr = nwg & 7;
  const int xcd = bid & 7, idx = bid >> 3;
  const int k = (xcd < rr ? xcd * (qq + 1) : rr * (qq + 1) + (xcd - rr) * qq) + idx;
  const int fullb = Mtiles >> 2;
  const int kfull = fullb * 4 * Ntiles;
  if (k < kfull){
    int band = k / (4 * Ntiles), rem = k % (4 * Ntiles);
    tn = rem >> 2; tm = band * 4 + (rem & 3);
  } else {
    int rem = k - kfull, bh = Mtiles - fullb * 4;
    tn = rem / bh; tm = fullb * 4 + rem % bh;
  }
}

// ---------------- fused prologue: weight casts + layout preps + im2col1 + vzero ----------------
// One dispatch, partitioned by blockIdx range (best-measured prologue config, R1).
__global__ __launch_bounds__(256) void prologue_k(
    const float* __restrict__ s0, const float* __restrict__ s1,
    const float* __restrict__ s2, const float* __restrict__ s3,
    const float* __restrict__ s4, unsigned short* __restrict__ dst,
    const float* __restrict__ c1w, unsigned short* __restrict__ oc1,
    const float* __restrict__ c2w, unsigned short* __restrict__ oc2,
    const float* __restrict__ pw, unsigned short* __restrict__ opos,
    const float* __restrict__ feats, unsigned short* __restrict__ ocol,
    unsigned short* __restrict__ vT)
{
  const int bid = blockIdx.x;
  const int tid = threadIdx.x;
  if (bid < 30648){
    // cast: i indexes 8-float groups; 62767104 floats total
    const int i = bid * 256 + tid;
    const float* s; int off;
    if (i < 1769472){ s = s0; off = i; }                       // Wqkv 14155776 f
    else if (i < 2359296){ s = s1; off = i - 1769472; }        // Wo   4718592 f
    else if (i < 4718592){ s = s2; off = i - 2359296; }        // W1  18874368 f
    else if (i < 7077888){ s = s3; off = i - 4718592; }        // W2  18874368 f
    else { s = s4; off = i - 7077888; }                        // proj 6144000 f
    const float4* sp = (const float4*)s + ((size_t)off << 1);
    float4 va = sp[0];
    float4 vb = sp[1];
    ushort8v o;
    o[0] = f2bf(va.x); o[1] = f2bf(va.y); o[2] = f2bf(va.z); o[3] = f2bf(va.w);
    o[4] = f2bf(vb.x); o[5] = f2bf(vb.y); o[6] = f2bf(vb.z); o[7] = f2bf(vb.w);
    ((ushort8v*)dst)[i] = o;
  } else if (bid < 30904){
    const int i = (bid - 30648) * 256 + tid;   // < 65536
    int co = i >> 7, j = i & 127;
    float v = 0.f;
    if (j < 120){ int k = j / 40, ci = j % 40; v = c1w[(co * 40 + ci) * 3 + k]; }
    oc1[i] = f2bf(v);
  } else if (bid < 35512){
    const int i = (bid - 30904) * 256 + tid;   // < 1179648
    int co = i / 1536, j = i % 1536;
    int k = j >> 9, c = j & 511;
    oc2[i] = f2bf(c2w[(co * 512 + c) * 3 + k]);
  } else if (bid < 53944){
    const int i = (bid - 35512) * 256 + tid;   // < 4718592
    int ci = i & 63;
    int rest = i >> 6;
    int co = rest % kCG; rest /= kCG;
    int k = rest % kPKp;
    int g = rest / kPKp;
    float v = 0.f;
    if (ci < 48 && k < kPK) v = pw[((g * kCG + co) * 48 + ci) * kPK + k];
    opos[i] = f2bf(v);
  } else if (bid < 57943){
    const int i = (bid - 53944) * 256 + tid;   // < 1023744
    int r = i >> 7, j = i & 127;
    int b = r / kT1, t = r % kT1;
    float v = 0.f;
    if (j < 120){ int k = j / 40, f = j % 40; v = feats[((size_t)b * kTraw + 2 * t + k) * kF + f]; }
    ocol[i] = f2bf(v);
  } else {
    const int i = (bid - 57943) * 256 + tid;   // < 75264
    int t = kT + i % (kTP - kT);
    int r = i / (kTP - kT);
    vT[(size_t)r * kTP + t] = 0;
  }
}

__global__ void im2col2_k(const unsigned short* __restrict__ act1, unsigned short* __restrict__ out){
  int i = blockIdx.x * 256 + threadIdx.x;
  int n4 = kM * 192;
  if (i >= n4) return;
  int r = i / 192, u = i % 192;
  int b = r / kT, t = r % kT;
  int j = u * 8;
  int k = j >> 9, c = j & 511;
  *(int4*)(out + (size_t)r * 1536 + j) =
      *(const int4*)(act1 + ((size_t)(b * kT1 + 2 * t + k)) * 512 + c);
}

// ---------------- BK=32 GEMM (256 thr): 3-buffer rotation, counted vmcnt, opt split-K ----------------
// PART=1: bf16 partials to Cbf + z*Mm*Nn (bias/res applied in combine kernel).
template<int BM, int GELU, int BF16OUT, int F32OUT, int RES, int PERM, int VOUT, int PART>
__global__ __launch_bounds__(256, (BM == 64) ? 4 : 3) void gemm_k(
    const unsigned short* __restrict__ A, const unsigned short* __restrict__ Bw,
    const float* __restrict__ bias, float* Cf, unsigned short* Cbf,
    const float* res, unsigned short* vT, int Mtiles, int Ntiles, int Mm, int Nn, int Kk, int ldk)
{
  constexpr int MW = BM / 32;
  constexpr int LPT = (BM == 64) ? 3 : 4;
  __shared__ unsigned short smem[3 * (BM + 128) * 32];
  unsigned short* lsA0 = smem;
  unsigned short* lsB0 = smem + 3 * BM * 32;
  const int tid = threadIdx.x;
  const int lane = tid & 63, w = tid >> 6;
  const int wm = w >> 1, wn = w & 1;
  const int lo = lane & 15, hi = lane >> 4;
  const int NK = Kk >> 5;
  const int zc = blockIdx.z;
  A += (size_t)zc * Kk;
  Bw += (size_t)zc * Kk;

  int tm, tn;
  xcd_map(blockIdx.x, Mtiles, Ntiles, tm, tn);

  auto stage = [&](int buf, int kt){
    #pragma unroll
    for (int p = 0; p < BM / 64; ++p){
      int row = p * 64 + (tid >> 2);
      int ga = min(tm * BM + row, Mm - 1);
      int sl = (tid & 3) ^ ((row >> 1) & 3);
      gl2lds16(A + (size_t)ga * ldk + kt * 32 + sl * 8, lsA0 + buf * BM * 32 + (p * 64 + w * 16) * 32);
    }
    #pragma unroll
    for (int p = 0; p < 2; ++p){
      int row = p * 64 + (tid >> 2);
      int gb = min(tn * 128 + row, Nn - 1);
      int sl = (tid & 3) ^ ((row >> 1) & 3);
      gl2lds16(Bw + (size_t)gb * ldk + kt * 32 + sl * 8, lsB0 + buf * 128 * 32 + (p * 64 + w * 16) * 32);
    }
  };

  f32x4 acc[MW][4];
  #pragma unroll
  for (int m = 0; m < MW; m++)
    #pragma unroll
    for (int n = 0; n < 4; n++) acc[m][n] = f32x4{0.f, 0.f, 0.f, 0.f};

  stage(0, 0);
  stage(1, 1);

  for (int kt = 0; kt < NK; ++kt){
    if (kt + 1 < NK){
      if (LPT == 3) asm volatile("s_waitcnt vmcnt(3)" ::: "memory");
      else          asm volatile("s_waitcnt vmcnt(4)" ::: "memory");
    } else {
      asm volatile("s_waitcnt vmcnt(0)" ::: "memory");
    }
    asm volatile("s_barrier" ::: "memory");
    const unsigned short* As = lsA0 + (kt % 3) * BM * 32;
    const unsigned short* Bs = lsB0 + (kt % 3) * 128 * 32;
    short8 af[MW], bfv[4];
    #pragma unroll
    for (int m = 0; m < MW; m++){
      int row = wm * (16 * MW) + m * 16 + lo;
      int sp = hi ^ ((row >> 1) & 3);
      af[m] = *(const short8*)&As[row * 32 + sp * 8];
    }
    #pragma unroll
    for (int n = 0; n < 4; n++){
      int row = wn * 64 + n * 16 + lo;
      int sp = hi ^ ((row >> 1) & 3);
      bfv[n] = *(const short8*)&Bs[row * 32 + sp * 8];
    }
    if (kt + 2 < NK) stage((kt + 2) % 3, kt + 2);
    __builtin_amdgcn_s_setprio(1);
    #pragma unroll
    for (int m = 0; m < MW; m++)
      #pragma unroll
      for (int n = 0; n < 4; n++)
        acc[m][n] = __builtin_amdgcn_mfma_f32_16x16x32_bf16(af[m], bfv[n], acc[m][n], 0, 0, 0);
    __builtin_amdgcn_s_setprio(0);
  }

  __syncthreads();
  float* esm = (float*)smem + w * (16 * 68);
  const size_t zoff = (size_t)zc * Mm * Nn;
  #pragma unroll
  for (int m = 0; m < MW; m++){
    #pragma unroll
    for (int n = 0; n < 4; n++)
      #pragma unroll
      for (int r = 0; r < 4; r++)
        esm[(hi * 4 + r) * 68 + n * 16 + lo] = acc[m][n][r];
    #pragma unroll
    for (int rr = 0; rr < 4; rr++){
      const int lr = rr * 4 + hi;
      const int lc = lo * 4;
      float4 v = *(float4*)&esm[lr * 68 + lc];
      const int row = tm * BM + wm * (16 * MW) + m * 16 + lr;
      const int col = tn * 128 + wn * 64 + lc;
      if (row < Mm && col < Nn){
        if (PART){
          ushort4v u; u.x = f2bf(v.x); u.y = f2bf(v.y); u.z = f2bf(v.z); u.w = f2bf(v.w);
          *(ushort4v*)&Cbf[zoff + (size_t)row * Nn + col] = u;
        } else {
          float4 b4 = *(const float4*)&bias[col];
          float o0 = v.x + b4.x, o1 = v.y + b4.y, o2 = v.z + b4.z, o3 = v.w + b4.w;
          if (GELU){ o0 = gelu_f(o0); o1 = gelu_f(o1); o2 = gelu_f(o2); o3 = gelu_f(o3); }
          if (RES){
            float4 r4 = *(const float4*)&res[(size_t)row * Nn + col];
            o0 += r4.x; o1 += r4.y; o2 += r4.z; o3 += r4.w;
          }
          if (F32OUT){
            int orow = PERM ? ((row % kT) * kB + row / kT) : row;
            float4 u; u.x = o0; u.y = o1; u.z = o2; u.w = o3;
            *(float4*)&Cf[(size_t)orow * Nn + col] = u;
          }
          if (BF16OUT){
            if (!VOUT || col < 1536){  // V-columns only live in vT
              ushort4v u; u.x = f2bf(o0); u.y = f2bf(o1); u.z = f2bf(o2); u.w = f2bf(o3);
              *(ushort4v*)&Cbf[(size_t)row * Nn + col] = u;
            }
          }
          if (VOUT && col >= 1536){
            int bb = row / kT, tt = row % kT;
            float ov[4] = {o0, o1, o2, o3};
            #pragma unroll
            for (int j = 0; j < 4; j++){
              int cj = col + j;
              int hh = (cj - 1536) >> 6, dd = (cj - 1536) & 63;
              vT[(((size_t)(bb * kH + hh)) * kDH + dd) * kTP + tt] = f2bf(ov[j]);
            }
          }
        }
      }
    }
  }
}

// ---------------- BK=32 GEMM (512 thr, BM=128 x BN=256) — proj ----------------
template<int GELU, int BF16OUT, int F32OUT, int RES, int PERM, int VOUT>
__global__ __launch_bounds__(512, 2) void gemm512_k(
    const unsigned short* __restrict__ A, const unsigned short* __restrict__ Bw,
    const float* __restrict__ bias, float* Cf, unsigned short* Cbf,
    const float* res, unsigned short* vT, int Mtiles, int Ntiles, int Mm, int Nn, int Kk)
{
  __shared__ unsigned short smem[3 * (128 + 256) * 32];
  unsigned short* lsA0 = smem;
  unsigned short* lsB0 = smem + 3 * 128 * 32;
  const int tid = threadIdx.x;
  const int lane = tid & 63, w = tid >> 6;
  const int wm = w >> 2, wn = w & 3;
  const int lo = lane & 15, hi = lane >> 4;
  const int NK = Kk >> 5;

  int tm, tn;
  xcd_map(blockIdx.x, Mtiles, Ntiles, tm, tn);

  auto stage = [&](int buf, int kt){
    {
      int row = tid >> 2;
      int ga = min(tm * 128 + row, Mm - 1);
      int sl = (tid & 3) ^ ((row >> 1) & 3);
      gl2lds16(A + (size_t)ga * Kk + kt * 32 + sl * 8, lsA0 + buf * 128 * 32 + (w * 16) * 32);
    }
    #pragma unroll
    for (int p = 0; p < 2; ++p){
      int row = p * 128 + (tid >> 2);
      int gb = min(tn * 256 + row, Nn - 1);
      int sl = (tid & 3) ^ ((row >> 1) & 3);
      gl2lds16(Bw + (size_t)gb * Kk + kt * 32 + sl * 8, lsB0 + buf * 256 * 32 + (p * 128 + w * 16) * 32);
    }
  };

  f32x4 acc[4][4];
  #pragma unroll
  for (int m = 0; m < 4; m++)
    #pragma unroll
    for (int n = 0; n < 4; n++) acc[m][n] = f32x4{0.f, 0.f, 0.f, 0.f};

  stage(0, 0);
  stage(1, 1);

  for (int kt = 0; kt < NK; ++kt){
    if (kt + 1 < NK) asm volatile("s_waitcnt vmcnt(3)" ::: "memory");
    else             asm volatile("s_waitcnt vmcnt(0)" ::: "memory");
    asm volatile("s_barrier" ::: "memory");
    const unsigned short* As = lsA0 + (kt % 3) * 128 * 32;
    const unsigned short* Bs = lsB0 + (kt % 3) * 256 * 32;
    short8 af[4], bfv[4];
    #pragma unroll
    for (int m = 0; m < 4; m++){
      int row = wm * 64 + m * 16 + lo;
      int sp = hi ^ ((row >> 1) & 3);
      af[m] = *(const short8*)&As[row * 32 + sp * 8];
    }
    #pragma unroll
    for (int n = 0; n < 4; n++){
      int row = wn * 64 + n * 16 + lo;
      int sp = hi ^ ((row >> 1) & 3);
      bfv[n] = *(const short8*)&Bs[row * 32 + sp * 8];
    }
    if (kt + 2 < NK) stage((kt + 2) % 3, kt + 2);
    __builtin_amdgcn_s_setprio(1);
    #pragma unroll
    for (int m = 0; m < 4; m++)
      #pragma unroll
      for (int n = 0; n < 4; n++)
        acc[m][n] = __builtin_amdgcn_mfma_f32_16x16x32_bf16(af[m], bfv[n], acc[m][n], 0, 0, 0);
    __builtin_amdgcn_s_setprio(0);
  }

  __syncthreads();
  float* esm = (float*)smem + w * (16 * 68);
  #pragma unroll
  for (int m = 0; m < 4; m++){
    #pragma unroll
    for (int n = 0; n < 4; n++)
      #pragma unroll
      for (int r = 0; r < 4; r++)
        esm[(hi * 4 + r) * 68 + n * 16 + lo] = acc[m][n][r];
    #pragma unroll
    for (int rr = 0; rr < 4; rr++){
      const int lr = rr * 4 + hi;
      const int lc = lo * 4;
      float4 v = *(float4*)&esm[lr * 68 + lc];
      const int row = tm * 128 + wm * 64 + m * 16 + lr;
      const int col = tn * 256 + wn * 64 + lc;
      if (row < Mm && col < Nn){
        float4 b4 = *(const float4*)&bias[col];
        float o0 = v.x + b4.x, o1 = v.y + b4.y, o2 = v.z + b4.z, o3 = v.w + b4.w;
        if (GELU){ o0 = gelu_f(o0); o1 = gelu_f(o1); o2 = gelu_f(o2); o3 = gelu_f(o3); }
        if (RES){
          float4 r4 = *(const float4*)&res[(size_t)row * Nn + col];
          o0 += r4.x; o1 += r4.y; o2 += r4.z; o3 += r4.w;
        }
        if (F32OUT){
          int orow = PERM ? ((row % kT) * kB + row / kT) : row;
          float4 u; u.x = o0; u.y = o1; u.z = o2; u.w = o3;
          *(float4*)&Cf[(size_t)orow * Nn + col] = u;
        }
        if (BF16OUT){
          ushort4v u; u.x = f2bf(o0); u.y = f2bf(o1); u.z = f2bf(o2); u.w = f2bf(o3);
          *(ushort4v*)&Cbf[(size_t)row * Nn + col] = u;
        }
      }
    }
  }
}

// ---------------- LayerNorm over D=768, 4 rows per 256-thread block ----------------
template<int OUTBF>
__global__ __launch_bounds__(256) void ln_k(const float* __restrict__ x, const float* __restrict__ gg,
    const float* __restrict__ bb, float* __restrict__ of, unsigned short* __restrict__ ob)
{
  const int row = blockIdx.x * 4 + (threadIdx.x >> 6);
  if (row >= kM) return;
  const int lane = threadIdx.x & 63;
  const float* xr = x + (size_t)row * kD;
  float4 v0 = *(const float4*)(xr + lane * 4);
  float4 v1 = *(const float4*)(xr + 256 + lane * 4);
  float4 v2 = *(const float4*)(xr + 512 + lane * 4);
  float s = v0.x + v0.y + v0.z + v0.w + v1.x + v1.y + v1.z + v1.w + v2.x + v2.y + v2.z + v2.w;
  #pragma unroll
  for (int o = 32; o >= 1; o >>= 1) s += __shfl_xor(s, o);
  const float mean = s * (1.0f / 768.0f);
  float q = 0.f;
  {
    float dx, dy, dz, dw;
    dx = v0.x - mean; dy = v0.y - mean; dz = v0.z - mean; dw = v0.w - mean; q += dx*dx + dy*dy + dz*dz + dw*dw;
    dx = v1.x - mean; dy = v1.y - mean; dz = v1.z - mean; dw = v1.w - mean; q += dx*dx + dy*dy + dz*dz + dw*dw;
    dx = v2.x - mean; dy = v2.y - mean; dz = v2.z - mean; dw = v2.w - mean; q += dx*dx + dy*dy + dz*dz + dw*dw;
  }
  #pragma unroll
  for (int o = 32; o >= 1; o >>= 1) q += __shfl_xor(q, o);
  const float rstd = rsqrtf(q * (1.0f / 768.0f) + 1e-5f);
  #pragma unroll
  for (int j = 0; j < 3; j++){
    float4 v = (j == 0) ? v0 : ((j == 1) ? v1 : v2);
    int c0 = j * 256 + lane * 4;
    float4 g4 = *(const float4*)(gg + c0);
    float4 b4 = *(const float4*)(bb + c0);
    float o0 = (v.x - mean) * rstd * g4.x + b4.x;
    float o1 = (v.y - mean) * rstd * g4.y + b4.y;
    float o2 = (v.z - mean) * rstd * g4.z + b4.z;
    float o3 = (v.w - mean) * rstd * g4.w + b4.w;
    if (OUTBF){
      ushort4v u; u.x = f2bf(o0); u.y = f2bf(o1); u.z = f2bf(o2); u.w = f2bf(o3);
      *(ushort4v*)(ob + (size_t)row * kD + c0) = u;
    } else {
      float4 u; u.x = o0; u.y = o1; u.z = o2; u.w = o3;
      *(float4*)(of + (size_t)row * kD + c0) = u;
    }
  }
}

// ---------------- fused double LayerNorm: y = LN(x; g0,b0) -> xo (f32); LN(y; g1,b1) -> hb (bf16) ----------------
__global__ __launch_bounds__(256) void lnln_k(const float* __restrict__ x,
    const float* __restrict__ g0v, const float* __restrict__ b0v,
    const float* __restrict__ g1v, const float* __restrict__ b1v,
    float* __restrict__ xo, unsigned short* __restrict__ hb)
{
  const int row = blockIdx.x * 4 + (threadIdx.x >> 6);
  if (row >= kM) return;
  const int lane = threadIdx.x & 63;
  const float* xr = x + (size_t)row * kD;
  float y[12];
  {
    float4 v0 = *(const float4*)(xr + lane * 4);
    float4 v1 = *(const float4*)(xr + 256 + lane * 4);
    float4 v2 = *(const float4*)(xr + 512 + lane * 4);
    float s = v0.x + v0.y + v0.z + v0.w + v1.x + v1.y + v1.z + v1.w + v2.x + v2.y + v2.z + v2.w;
    #pragma unroll
    for (int o = 32; o >= 1; o >>= 1) s += __shfl_xor(s, o);
    const float mean = s * (1.0f / 768.0f);
    float q = 0.f;
    float xv[12] = {v0.x, v0.y, v0.z, v0.w, v1.x, v1.y, v1.z, v1.w, v2.x, v2.y, v2.z, v2.w};
    #pragma unroll
    for (int t = 0; t < 12; t++){ float d = xv[t] - mean; q += d * d; }
    #pragma unroll
    for (int o = 32; o >= 1; o >>= 1) q += __shfl_xor(q, o);
    const float rstd = rsqrtf(q * (1.0f / 768.0f) + 1e-5f);
    #pragma unroll
    for (int j = 0; j < 3; j++){
      const int c0 = j * 256 + lane * 4;
      float4 g4 = *(const float4*)(g0v + c0);
      float4 b4 = *(const float4*)(b0v + c0);
      y[j*4+0] = (xv[j*4+0] - mean) * rstd * g4.x + b4.x;
      y[j*4+1] = (xv[j*4+1] - mean) * rstd * g4.y + b4.y;
      y[j*4+2] = (xv[j*4+2] - mean) * rstd * g4.z + b4.z;
      y[j*4+3] = (xv[j*4+3] - mean) * rstd * g4.w + b4.w;
      float4 u; u.x = y[j*4+0]; u.y = y[j*4+1]; u.z = y[j*4+2]; u.w = y[j*4+3];
      *(float4*)(xo + (size_t)row * kD + c0) = u;
    }
  }
  {
    float s = 0.f;
    #pragma unroll
    for (int t = 0; t < 12; t++) s += y[t];
    #pragma unroll
    for (int o = 32; o >= 1; o >>= 1) s += __shfl_xor(s, o);
    const float mean = s * (1.0f / 768.0f);
    float q = 0.f;
    #pragma unroll
    for (int t = 0; t < 12; t++){ float d = y[t] - mean; q += d * d; }
    #pragma unroll
    for (int o = 32; o >= 1; o >>= 1) q += __shfl_xor(q, o);
    const float rstd = rsqrtf(q * (1.0f / 768.0f) + 1e-5f);
    #pragma unroll
    for (int j = 0; j < 3; j++){
      const int c0 = j * 256 + lane * 4;
      float4 g4 = *(const float4*)(g1v + c0);
      float4 b4 = *(const float4*)(b1v + c0);
      ushort4v u;
      u.x = f2bf((y[j*4+0] - mean) * rstd * g4.x + b4.x);
      u.y = f2bf((y[j*4+1] - mean) * rstd * g4.y + b4.y);
      u.z = f2bf((y[j*4+2] - mean) * rstd * g4.z + b4.z);
      u.w = f2bf((y[j*4+3] - mean) * rstd * g4.w + b4.w);
      *(ushort4v*)(hb + (size_t)row * kD + c0) = u;
    }
  }
}

// ---------------- combine 2 bf16 W2 partials + bias + residual -> x; then LN (or bf16 cast) ----------------
template<int LNOUT, int WRITEX>
__global__ __launch_bounds__(256) void cmbln_k(const unsigned short* __restrict__ p0,
    const unsigned short* __restrict__ p1,
    const float* __restrict__ bias, float* __restrict__ x, const float* __restrict__ gg,
    const float* __restrict__ bb, unsigned short* __restrict__ ob)
{
  const int row = blockIdx.x * 4 + (threadIdx.x >> 6);
  if (row >= kM) return;
  const int lane = threadIdx.x & 63;
  const size_t base = (size_t)row * kD;
  float xn[12];
  #pragma unroll
  for (int j = 0; j < 3; j++){
    const int c0 = j * 256 + lane * 4;
    float4 xv = *(const float4*)&x[base + c0];
    ushort4v a = *(const ushort4v*)&p0[base + c0];
    ushort4v bv = *(const ushort4v*)&p1[base + c0];
    float4 bs = *(const float4*)&bias[c0];
    xn[j*4+0] = xv.x + bf2f(a.x) + bf2f(bv.x) + bs.x;
    xn[j*4+1] = xv.y + bf2f(a.y) + bf2f(bv.y) + bs.y;
    xn[j*4+2] = xv.z + bf2f(a.z) + bf2f(bv.z) + bs.z;
    xn[j*4+3] = xv.w + bf2f(a.w) + bf2f(bv.w) + bs.w;
    if (WRITEX){
      float4 u; u.x = xn[j*4+0]; u.y = xn[j*4+1]; u.z = xn[j*4+2]; u.w = xn[j*4+3];
      *(float4*)&x[base + c0] = u;
    }
  }
  if (LNOUT){
    float s = 0.f;
    #pragma unroll
    for (int t = 0; t < 12; t++) s += xn[t];
    #pragma unroll
    for (int o = 32; o >= 1; o >>= 1) s += __shfl_xor(s, o);
    const float mean = s * (1.0f / 768.0f);
    float q = 0.f;
    #pragma unroll
    for (int t = 0; t < 12; t++){ float d = xn[t] - mean; q += d * d; }
    #pragma unroll
    for (int o = 32; o >= 1; o >>= 1) q += __shfl_xor(q, o);
    const float rstd = rsqrtf(q * (1.0f / 768.0f) + 1e-5f);
    #pragma unroll
    for (int j = 0; j < 3; j++){
      const int c0 = j * 256 + lane * 4;
      float4 g4 = *(const float4*)(gg + c0);
      float4 b4 = *(const float4*)(bb + c0);
      ushort4v u;
      u.x = f2bf((xn[j*4+0] - mean) * rstd * g4.x + b4.x);
      u.y = f2bf((xn[j*4+1] - mean) * rstd * g4.y + b4.y);
      u.z = f2bf((xn[j*4+2] - mean) * rstd * g4.z + b4.z);
      u.w = f2bf((xn[j*4+3] - mean) * rstd * g4.w + b4.w);
      *(ushort4v*)(ob + base + c0) = u;
    }
  } else {
    #pragma unroll
    for (int j = 0; j < 3; j++){
      const int c0 = j * 256 + lane * 4;
      ushort4v u;
      u.x = f2bf(xn[j*4+0]); u.y = f2bf(xn[j*4+1]);
      u.z = f2bf(xn[j*4+2]); u.w = f2bf(xn[j*4+3]);
      *(ushort4v*)(ob + base + c0) = u;
    }
  }
}

// ---------------- grouped positional conv (K=95, SAME) via MFMA, LDS weights ----------------
__global__ __launch_bounds__(256) void posconv_k(const float* __restrict__ x0,
    const unsigned short* __restrict__ wp, const float* __restrict__ pb, float* __restrict__ xsum)
{
  __shared__ unsigned short xs[224 * 64];
  __shared__ unsigned short wl[2][2 * 48 * 64];
  const int tid = threadIdx.x, lane = tid & 63, w = tid >> 6;
  const int t0 = blockIdx.x * 128, g = blockIdx.y, b = blockIdx.z;
  const int cg0 = g * kCG;
  for (int e = tid; e < 224 * 64; e += 256){
    int tr = e >> 6, ci = e & 63;
    int t = t0 - 47 + tr;
    unsigned short val = 0;
    if (ci < 48 && t >= 0 && t < kT) val = f2bf(x0[((size_t)(b * kT + t)) * kD + cg0 + ci]);
    xs[(tr * 8 + ((ci >> 3) ^ (tr & 7))) * 8 + (ci & 7)] = val;
  }
  const unsigned short* wg = wp + (size_t)g * kPKp * kCG * 64;
  auto stageW = [&](int buf, int c){
    const unsigned short* src = wg + (size_t)c * 2 * kCG * 64;
    #pragma unroll
    for (int j = 0; j < 3; j++){
      int row = w * 24 + j * 8 + (lane >> 3);
      int slot = (lane & 7) ^ (row & 7);
      gl2lds16(src + (size_t)row * 64 + slot * 8, &wl[buf][(w * 24 + j * 8) * 64]);
    }
  };
  stageW(0, 0);

  f32x4 acc[2][3];
  #pragma unroll
  for (int rg = 0; rg < 2; rg++)
    #pragma unroll
    for (int f = 0; f < 3; f++) acc[rg][f] = f32x4{0.f, 0.f, 0.f, 0.f};

  const int lo = lane & 15, hi = lane >> 4;
  for (int c = 0; c < 48; ++c){
    __syncthreads();
    if (c + 1 < 48) stageW((c + 1) & 1, c + 1);
    const int buf = c & 1;
    #pragma unroll
    for (int kk = 0; kk < 2; kk++){
      const int k = c * 2 + kk;
      short8 a0[2], a1[2];
      #pragma unroll
      for (int rg = 0; rg < 2; rg++){
        const int row0 = w * 32 + rg * 16 + lo + k;
        a0[rg] = *(const short8*)&xs[(row0 * 8 + ((hi    ) ^ (row0 & 7))) * 8];
        a1[rg] = *(const short8*)&xs[(row0 * 8 + ((hi + 4) ^ (row0 & 7))) * 8];
      }
      #pragma unroll
      for (int f = 0; f < 3; f++){
        const int wr = kk * 48 + f * 16 + lo;
        short8 b0 = *(const short8*)&wl[buf][(wr * 8 + ((hi    ) ^ (wr & 7))) * 8];
        short8 b1 = *(const short8*)&wl[buf][(wr * 8 + ((hi + 4) ^ (wr & 7))) * 8];
        #pragma unroll
        for (int rg = 0; rg < 2; rg++){
          acc[rg][f] = __builtin_amdgcn_mfma_f32_16x16x32_bf16(a0[rg], b0, acc[rg][f], 0, 0, 0);
          acc[rg][f] = __builtin_amdgcn_mfma_f32_16x16x32_bf16(a1[rg], b1, acc[rg][f], 0, 0, 0);
        }
      }
    }
  }
  #pragma unroll
  for (int rg = 0; rg < 2; rg++){
    #pragma unroll
    for (int f = 0; f < 3; f++){
      #pragma unroll
      for (int r = 0; r < 4; r++){
        int t = t0 + w * 32 + rg * 16 + (hi << 2) + r;
        int co = f * 16 + lo;
        if (t < kT){
          size_t idx = ((size_t)(b * kT + t)) * kD + cg0 + co;
          xsum[idx] = x0[idx] + gelu_f(acc[rg][f][r] + pb[cg0 + co]);
        }
      }
    }
  }
}

// ---------------- split-K flash attention: bf16 chunk partials (additive, fixed-max) ----------------
// (original structure; kNCH=2 -> 16 tiles per chunk, half the partial traffic)
__global__ __launch_bounds__(256) void attn_k(const unsigned short* __restrict__ qkv,
    const unsigned short* __restrict__ vT, unsigned short* __restrict__ pO, float* __restrict__ plsum,
    const float* __restrict__ alibi_scale)
{
  const int tid = threadIdx.x, lane = tid & 63, w = tid >> 6;
  const int qb = blockIdx.x;
  const int cx = blockIdx.y / kH, h = blockIdx.y % kH;
  const int b = blockIdx.z;
  const float slope = exp2f(-8.0f * (float)(h + 1) * (1.0f / 12.0f)) * fmaxf(alibi_scale[h], 0.f);
  const float c1 = 0.125f * 1.44269504f;
  const float sl2 = slope * 1.44269504f;
  const float M2 = 12.0f * 1.44269504f;

  int ktlo, kthi;
  {
    float Wf = (slope > 1e-8f) ? kWIN / slope : 2048.0f;
    int W = (int)fminf(Wf, 2048.0f);
    int jlo = max(0, qb * 128 - W);
    int jhi = min(kT - 1, qb * 128 + 127 + W);
    ktlo = jlo >> 6; kthi = jhi >> 6;
  }
  ktlo = max(ktlo, cx * kCT);
  kthi = min(kthi, cx * kCT + kCT - 1);
  if (ktlo > kthi) return;

  __shared__ unsigned short Kl[2][64 * 64];
  __shared__ unsigned short Vl[2][64 * 64];
  __shared__ unsigned short Pl[4][32 * 72];
  const int q0 = qb * 128 + w * 32;
  const int lo = lane & 15, hi = lane >> 4;

  short8 aq[2][2];
  #pragma unroll
  for (int qa = 0; qa < 2; qa++){
    const int qr = min(q0 + qa * 16 + lo, kT - 1);
    const unsigned short* qbase = qkv + ((size_t)(b * kT + qr)) * 2304 + h * 64 + hi * 8;
    aq[qa][0] = *(const short8*)(qbase);
    aq[qa][1] = *(const short8*)(qbase + 32);
  }

  f32x4 oacc[2][4];
  #pragma unroll
  for (int qa = 0; qa < 2; qa++)
    #pragma unroll
    for (int f = 0; f < 4; f++) oacc[qa][f] = f32x4{0.f, 0.f, 0.f, 0.f};
  float lrow[2][4];
  #pragma unroll
  for (int qa = 0; qa < 2; qa++)
    #pragma unroll
    for (int r = 0; r < 4; r++) lrow[qa][r] = 0.f;

  const unsigned short* kbase = qkv + (size_t)b * kT * 2304 + 768 + h * 64;
  const unsigned short* vbase = vT + ((size_t)(b * kH + h)) * kDH * kTP;
  unsigned short* pl = &Pl[w][0];

  auto stageKV = [&](int buf, int kt){
    const int j0 = kt * 64;
    #pragma unroll
    for (int c = 0; c < 2; c++){
      int row = w * 16 + c * 8 + (lane >> 3);
      int slot = (lane & 7) ^ (row & 7);
      int kr = min(j0 + row, kT - 1);
      gl2lds16(kbase + (size_t)kr * 2304 + slot * 8, &Kl[buf][(w * 16 + c * 8) * 64]);
      gl2lds16(vbase + (size_t)row * kTP + j0 + slot * 8, &Vl[buf][(w * 16 + c * 8) * 64]);
    }
  };
  stageKV(ktlo & 1, ktlo);

  for (int kt = ktlo; kt <= kthi; ++kt){
    __syncthreads();
    if (kt + 1 <= kthi) stageKV((kt + 1) & 1, kt + 1);
    const int buf = kt & 1;
    const int j0 = kt * 64;
    f32x4 sac[2][4];
    __builtin_amdgcn_s_setprio(1);
    #pragma unroll
    for (int f = 0; f < 4; f++){
      const int krow = f * 16 + lo;
      short8 b0 = *(const short8*)&Kl[buf][(krow * 8 + ((hi    ) ^ (krow & 7))) * 8];
      short8 b1 = *(const short8*)&Kl[buf][(krow * 8 + ((hi + 4) ^ (krow & 7))) * 8];
      #pragma unroll
      for (int qa = 0; qa < 2; qa++){
        f32x4 s = f32x4{0.f, 0.f, 0.f, 0.f};
        s = __builtin_amdgcn_mfma_f32_16x16x32_bf16(aq[qa][0], b0, s, 0, 0, 0);
        s = __builtin_amdgcn_mfma_f32_16x16x32_bf16(aq[qa][1], b1, s, 0, 0, 0);
        sac[qa][f] = s;
      }
    }
    __builtin_amdgcn_s_setprio(0);
    #pragma unroll
    for (int qa = 0; qa < 2; qa++){
      #pragma unroll
      for (int f = 0; f < 4; f++){
        const int j = j0 + f * 16 + lo;
        const float jf = (float)j;
        #pragma unroll
        for (int r = 0; r < 4; r++){
          const float qrow = (float)(q0 + qa * 16 + hi * 4 + r);
          float sv = sac[qa][f][r] * c1 - fabsf(qrow - jf) * sl2 - M2;
          if (j >= kT) sv = -1.0e30f;
          float e = exp2f(sv);
          lrow[qa][r] += e;
          pl[(qa * 16 + hi * 4 + r) * 72 + f * 16 + lo] = f2bf(e);
        }
      }
    }
    __builtin_amdgcn_s_setprio(1);
    #pragma unroll
    for (int c2 = 0; c2 < 2; c2++){
      short8 pa[2];
      #pragma unroll
      for (int qa = 0; qa < 2; qa++)
        pa[qa] = *(const short8*)&pl[(qa * 16 + lo) * 72 + c2 * 32 + hi * 8];
      #pragma unroll
      for (int f = 0; f < 4; f++){
        const int dr = f * 16 + lo;
        short8 bv = *(const short8*)&Vl[buf][(dr * 8 + ((c2 * 4 + hi) ^ (dr & 7))) * 8];
        #pragma unroll
        for (int qa = 0; qa < 2; qa++)
          oacc[qa][f] = __builtin_amdgcn_mfma_f32_16x16x32_bf16(pa[qa], bv, oacc[qa][f], 0, 0, 0);
      }
    }
    __builtin_amdgcn_s_setprio(0);
  }
  const int pidx = (cx * kB + b) * kH + h;
  unsigned short* po = pO + (size_t)pidx * kTP * 64;
  #pragma unroll
  for (int o = 1; o < 16; o <<= 1){
    #pragma unroll
    for (int qa = 0; qa < 2; qa++)
      #pragma unroll
      for (int r = 0; r < 4; r++) lrow[qa][r] += __shfl_xor(lrow[qa][r], o);
  }
  #pragma unroll
  for (int qa = 0; qa < 2; qa++){
    #pragma unroll
    for (int f = 0; f < 4; f++){
      #pragma unroll
      for (int r = 0; r < 4; r++){
        int q = q0 + qa * 16 + hi * 4 + r;
        if (q < kT) po[(size_t)q * 64 + f * 16 + lo] = f2bf(oacc[qa][f][r]);
      }
    }
  }
  if (lo == 0){
    #pragma unroll
    for (int qa = 0; qa < 2; qa++)
      #pragma unroll
      for (int r = 0; r < 4; r++){
        int q = q0 + qa * 16 + hi * 4 + r;
        if (q < kT) plsum[(size_t)pidx * kTP + q] = lrow[qa][r];
      }
  }
}

// ---------------- attention chunk-combine + normalize -> bf16 O ----------------
__global__ __launch_bounds__(256) void attnred_k(const unsigned short* __restrict__ pO,
    const float* __restrict__ plsum, const float* __restrict__ alibi_scale,
    unsigned short* __restrict__ obf)
{
  int i = blockIdx.x * 256 + threadIdx.x;
  const int total = kB * kH * kT * 16;
  if (i >= total) return;
  const int d4 = i & 15;
  int rest = i >> 4;
  const int q = rest % kT; rest /= kT;
  const int h = rest % kH;
  const int b = rest / kH;
  const float slope = exp2f(-8.0f * (float)(h + 1) * (1.0f / 12.0f)) * fmaxf(alibi_scale[h], 0.f);
  int ktlo, kthi;
  {
    float Wf = (slope > 1e-8f) ? kWIN / slope : 2048.0f;
    int W = (int)fminf(Wf, 2048.0f);
    const int qb = q >> 7;
    int jlo = max(0, qb * 128 - W);
    int jhi = min(kT - 1, qb * 128 + 127 + W);
    ktlo = jlo >> 6; kthi = jhi >> 6;
  }
  float a0 = 0.f, a1 = 0.f, a2 = 0.f, a3 = 0.f;
  float l = 0.f;
  #pragma unroll
  for (int c = 0; c < kNCH; c++){
    if (c * kCT + kCT - 1 >= ktlo && c * kCT <= kthi){
      const int pidx = (c * kB + b) * kH + h;
      ushort4v v = *(const ushort4v*)&pO[((size_t)pidx * kTP + q) * 64 + d4 * 4];
      a0 += bf2f(v.x); a1 += bf2f(v.y); a2 += bf2f(v.z); a3 += bf2f(v.w);
      l += plsum[(size_t)pidx * kTP + q];
    }
  }
  const float inv = 1.0f / l;
  ushort4v u;
  u.x = f2bf(a0 * inv); u.y = f2bf(a1 * inv);
  u.z = f2bf(a2 * inv); u.w = f2bf(a3 * inv);
  *(ushort4v*)&obf[((size_t)(b * kT + q)) * kD + h * 64 + d4 * 4] = u;
}

} // namespace

extern "C" void kernel_launch(void* const* d_in, const int* in_sizes, int n_in,
                              void* d_out, int out_size, void* d_ws, size_t ws_size,
                              hipStream_t stream)
{
  (void)in_sizes; (void)n_in; (void)out_size; (void)ws_size;
  const float* feats   = (const float*)d_in[0];
  const float* conv1_w = (const float*)d_in[1];
  const float* conv1_b = (const float*)d_in[2];
  const float* conv2_w = (const float*)d_in[3];
  const float* conv2_b = (const float*)d_in[4];
  const float* fln_g   = (const float*)d_in[5];
  const float* fln_b   = (const float*)d_in[6];
  const float* pos_w   = (const float*)d_in[7];
  const float* pos_b   = (const float*)d_in[8];
  const float* cln_g   = (const float*)d_in[9];
  const float* cln_b   = (const float*)d_in[10];
  const float* alibi   = (const float*)d_in[11];
  const float* Wqkv    = (const float*)d_in[12];
  const float* bqkv    = (const float*)d_in[13];
  const float* Wo      = (const float*)d_in[14];
  const float* bo      = (const float*)d_in[15];
  const float* ln1g    = (const float*)d_in[16];
  const float* ln1b    = (const float*)d_in[17];
  const float* ln2g    = (const float*)d_in[18];
  const float* ln2b    = (const float*)d_in[19];
  const float* W1      = (const float*)d_in[20];
  const float* b1      = (const float*)d_in[21];
  const float* W2      = (const float*)d_in[22];
  const float* b2      = (const float*)d_in[23];
  const float* projw   = (const float*)d_in[24];
  const float* projb   = (const float*)d_in[25];
  float* out = (float*)d_out;

  char* wsp = (char*)d_ws;
  size_t off = 0;
  auto alloc = [&](size_t nbytes)->char*{
    char* p = wsp + off;
    off += (nbytes + 255) & ~(size_t)255;
    return p;
  };
  // NOTE: the 5 bf16 weight buffers below are contiguous (all sizes % 256B == 0);
  // the prologue cast segment writes them as one region starting at wqkv_bf.
  unsigned short* wqkv_bf  = (unsigned short*)alloc((size_t)kL * 2304 * 768 * 2);
  unsigned short* wo_bf    = (unsigned short*)alloc((size_t)kL * 768 * 768 * 2);
  unsigned short* w1_bf    = (unsigned short*)alloc((size_t)kL * 3072 * 768 * 2);
  unsigned short* w2_bf    = (unsigned short*)alloc((size_t)kL * 768 * 3072 * 2);
  unsigned short* wproj_bf = (unsigned short*)alloc((size_t)kV * 768 * 2);
  unsigned short* wc1      = (unsigned short*)alloc((size_t)kC1 * 128 * 2);
  unsigned short* wc2      = (unsigned short*)alloc((size_t)kD * 1536 * 2);
  unsigned short* wpos     = (unsigned short*)alloc((size_t)kPG * kPKp * kCG * 64 * 2);
  // conv/prologue scratch — dead during the layer loop; attn/W2 partials alias this region
  char* pbase = wsp + off;
  unsigned short* a1col    = (unsigned short*)alloc((size_t)kM1 * 128 * 2);
  unsigned short* act1     = (unsigned short*)alloc((size_t)kM1 * 512 * 2);
  unsigned short* a2col    = (unsigned short*)alloc((size_t)kM * 1536 * 2);
  float* xa    = (float*)alloc((size_t)kM * 768 * 4);
  float* x0    = (float*)alloc((size_t)kM * 768 * 4);
  float* xsum  = (float*)alloc((size_t)kM * 768 * 4);
  float* x     = (float*)alloc((size_t)kM * 768 * 4);
  unsigned short* h_bf   = (unsigned short*)alloc((size_t)kM * 768 * 2);
  unsigned short* qkv_bf = (unsigned short*)alloc((size_t)kM * 2304 * 2);
  unsigned short* vTb    = (unsigned short*)alloc((size_t)kB * kH * kDH * kTP * 2);
  unsigned short* o_bf   = (unsigned short*)alloc((size_t)kM * 768 * 2);
  unsigned short* f_bf   = (unsigned short*)alloc((size_t)kM * 3072 * 2);
  unsigned short* xf_bf  = (unsigned short*)alloc((size_t)kM * 768 * 2);
  // aliases over dead prologue region: attn partials (13 MB) then W2 bf16 partials (12.3 MB)
  unsigned short* pO = (unsigned short*)pbase;
  float* plsum = (float*)(pbase + (size_t)kNCH * kB * kH * kTP * 64 * 2);
  unsigned short* pG = (unsigned short*)(pbase + (size_t)kNCH * kB * kH * kTP * 64 * 2
                                               + (size_t)kNCH * kB * kH * kTP * 4);
  unsigned short* pG1 = pG + (size_t)kM * 768;

  auto cgrid = [](size_t n){ return dim3((unsigned)((n + 255) / 256)); };

  // fused prologue: all weight casts/packs + im2col1 + vT zero-fill in ONE dispatch
  prologue_k<<<dim3(58237), 256, 0, stream>>>(Wqkv, Wo, W1, W2, projw, wqkv_bf,
      conv1_w, wc1, conv2_w, wc2, pos_w, wpos, feats, a1col, vTb);

  // conv1 (GEMM, K padded to 128) -> act1 bf16 with GELU
  gemm_k<128,1,1,0,0,0,0,0><<<dim3(63 * 4), 256, 0, stream>>>(a1col, wc1, conv1_b, nullptr, act1, nullptr, nullptr, 63, 4, kM1, 512, 128, 128);
  im2col2_k<<<cgrid((size_t)kM * 192), 256, 0, stream>>>(act1, a2col);
  // conv2 -> xa f32 with GELU
  gemm_k<64,1,0,1,0,0,0,0><<<dim3(63 * 6), 256, 0, stream>>>(a2col, wc2, conv2_b, xa, nullptr, nullptr, nullptr, 63, 6, kM, 768, 1536, 1536);
  ln_k<0><<<dim3(1000), 256, 0, stream>>>(xa, fln_g, fln_b, x0, nullptr);
  posconv_k<<<dim3(16, 16, 2), 256, 0, stream>>>(x0, wpos, pos_b, xsum);
  // fused: x = LN(xsum; ctx_ln), h_bf = LN(x; ln1[0])
  lnln_k<<<dim3(1000), 256, 0, stream>>>(xsum, cln_g, cln_b, ln1g, ln1b, x, h_bf);

  const int nred = kB * kH * kT * 16;
  for (int i = 0; i < kL; i++){
    // qkv GEMM with fused V-transpose epilogue (V cols only to vT)
    gemm_k<128,0,1,0,0,0,1,0><<<dim3(32 * 18), 256, 0, stream>>>(h_bf, wqkv_bf + (size_t)i * 2304 * 768,
        bqkv + i * 2304, nullptr, qkv_bf, nullptr, vTb, 32, 18, kM, 2304, 768, 768);
    attn_k<<<dim3(16, kH * kNCH, 2), 256, 0, stream>>>(qkv_bf, vTb, pO, plsum, alibi);
    attnred_k<<<cgrid(nred), 256, 0, stream>>>(pO, plsum, alibi, o_bf);
    gemm_k<64,0,0,1,1,0,0,0><<<dim3(63 * 6), 256, 0, stream>>>(o_bf, wo_bf + (size_t)i * 768 * 768,
        bo + i * 768, x, nullptr, x, nullptr, 63, 6, kM, 768, 768, 768);
    ln_k<1><<<dim3(1000), 256, 0, stream>>>(x, ln2g + i * 768, ln2b + i * 768, nullptr, h_bf);
    // W1 GEMM with GELU
    gemm_k<128,1,1,0,0,0,0,0><<<dim3(32 * 24), 256, 0, stream>>>(h_bf, w1_bf + (size_t)i * 3072 * 768,
        b1 + i * 3072, nullptr, f_bf, nullptr, nullptr, 32, 24, kM, 3072, 768, 768);
    // W2 split-K (2 x 1536) -> bf16 partials; combine + residual + next LN (or bf16 cast) fused
    gemm_k<64,0,0,0,0,0,0,1><<<dim3(63 * 6, 1, 2), 256, 0, stream>>>(f_bf, w2_bf + (size_t)i * 768 * 3072,
        nullptr, nullptr, pG, nullptr, nullptr, 63, 6, kM, 768, 1536, 3072);
    if (i < kL - 1){
      cmbln_k<1,1><<<dim3(1000), 256, 0, stream>>>(pG, pG1, b2 + i * 768, x,
          ln1g + (i + 1) * 768, ln1b + (i + 1) * 768, h_bf);
    } else {
      cmbln_k<0,0><<<dim3(1000), 256, 0, stream>>>(pG, pG1, b2 + i * 768, x,
          nullptr, nullptr, xf_bf);
    }
  }
  // final projection (512-thr, BM=128 x BN=256, 1024 blocks) with [t, b, v] output permutation
  gemm512_k<0,0,1,0,1,0><<<dim3(32 * 32), 512, 0, stream>>>(xf_bf, wproj_bf, projb, out, nullptr, nullptr, nullptr, 32, 32, kM, kV, 768);
}

// Round 9
// 1786.017 us; speedup vs baseline: 1.0058x; 1.0058x over previous
//
#include <hip/hip_runtime.h>
#include <math.h>

typedef __attribute__((ext_vector_type(8))) short short8;
typedef __attribute__((ext_vector_type(4))) float f32x4;
typedef __attribute__((ext_vector_type(4))) unsigned short ushort4v;
typedef __attribute__((ext_vector_type(8))) unsigned short ushort8v;

#define DEV static __device__ __forceinline__

namespace {

constexpr int kB = 2;
constexpr int kTraw = 8000;
constexpr int kF = 40;
constexpr int kT1 = 3999;
constexpr int kC1 = 512;
constexpr int kT = 1999;
constexpr int kD = 768;
constexpr int kM = kB * kT;    // 3998
constexpr int kM1 = kB * kT1;  // 7998
constexpr int kH = 12;
constexpr int kDH = 64;
constexpr int kL = 8;
constexpr int kV = 8000;
constexpr int kPK = 95;
constexpr int kPKp = 96;
constexpr int kPG = 16;
constexpr int kCG = 48;
constexpr int kTP = 2048;
constexpr int kNCH = 4;        // kv chunks (8 tiles each) — best-measured config (R7)
constexpr float kWIN = 8.0f;   // ALiBi window threshold (nats)

DEV unsigned short f2bf(float x){
  union{unsigned int i; float f;} v; v.f = x;
  unsigned int r = v.i + 0x7FFFu + ((v.i >> 16) & 1u);
  return (unsigned short)(r >> 16);
}
DEV float bf2f(unsigned short u){
  union{unsigned int i; float f;} v; v.i = ((unsigned int)u) << 16; return v.f;
}
DEV float gelu_f(float x){
  return 0.5f * x * (1.0f + tanhf(0.7978845608028654f * (x + 0.044715f * x * x * x)));
}
DEV void gl2lds16(const unsigned short* g, unsigned short* l){
  __builtin_amdgcn_global_load_lds(
      (const __attribute__((address_space(1))) unsigned int*)(g),
      (__attribute__((address_space(3))) unsigned int*)(l), 16, 0, 0);
}
DEV void xcd_map(int bid, int Mtiles, int Ntiles, int& tm, int& tn){
  const int nwg = Mtiles * Ntiles;
  const int qq = nwg >> 3, rr = nwg & 7;
  const int xcd = bid & 7, idx = bid >> 3;
  const int k = (xcd < rr ? xcd * (qq + 1) : rr * (qq + 1) + (xcd - rr) * qq) + idx;
  const int fullb = Mtiles >> 2;
  const int kfull = fullb * 4 * Ntiles;
  if (k < kfull){
    int band = k / (4 * Ntiles), rem = k % (4 * Ntiles);
    tn = rem >> 2; tm = band * 4 + (rem & 3);
  } else {
    int rem = k - kfull, bh = Mtiles - fullb * 4;
    tn = rem / bh; tm = fullb * 4 + rem % bh;
  }
}

// ---------------- fused prologue: weight casts + layout preps + im2col1 + vzero ----------------
// One dispatch, partitioned by blockIdx range (best-measured prologue config, R1/R7).
__global__ __launch_bounds__(256) void prologue_k(
    const float* __restrict__ s0, const float* __restrict__ s1,
    const float* __restrict__ s2, const float* __restrict__ s3,
    const float* __restrict__ s4, unsigned short* __restrict__ dst,
    const float* __restrict__ c1w, unsigned short* __restrict__ oc1,
    const float* __restrict__ c2w, unsigned short* __restrict__ oc2,
    const float* __restrict__ pw, unsigned short* __restrict__ opos,
    const float* __restrict__ feats, unsigned short* __restrict__ ocol,
    unsigned short* __restrict__ vT)
{
  const int bid = blockIdx.x;
  const int tid = threadIdx.x;
  if (bid < 30648){
    // cast: i indexes 8-float groups; 62767104 floats total
    const int i = bid * 256 + tid;
    const float* s; int off;
    if (i < 1769472){ s = s0; off = i; }                       // Wqkv 14155776 f
    else if (i < 2359296){ s = s1; off = i - 1769472; }        // Wo   4718592 f
    else if (i < 4718592){ s = s2; off = i - 2359296; }        // W1  18874368 f
    else if (i < 7077888){ s = s3; off = i - 4718592; }        // W2  18874368 f
    else { s = s4; off = i - 7077888; }                        // proj 6144000 f
    const float4* sp = (const float4*)s + ((size_t)off << 1);
    float4 va = sp[0];
    float4 vb = sp[1];
    ushort8v o;
    o[0] = f2bf(va.x); o[1] = f2bf(va.y); o[2] = f2bf(va.z); o[3] = f2bf(va.w);
    o[4] = f2bf(vb.x); o[5] = f2bf(vb.y); o[6] = f2bf(vb.z); o[7] = f2bf(vb.w);
    ((ushort8v*)dst)[i] = o;
  } else if (bid < 30904){
    const int i = (bid - 30648) * 256 + tid;   // < 65536
    int co = i >> 7, j = i & 127;
    float v = 0.f;
    if (j < 120){ int k = j / 40, ci = j % 40; v = c1w[(co * 40 + ci) * 3 + k]; }
    oc1[i] = f2bf(v);
  } else if (bid < 35512){
    const int i = (bid - 30904) * 256 + tid;   // < 1179648
    int co = i / 1536, j = i % 1536;
    int k = j >> 9, c = j & 511;
    oc2[i] = f2bf(c2w[(co * 512 + c) * 3 + k]);
  } else if (bid < 53944){
    const int i = (bid - 35512) * 256 + tid;   // < 4718592
    int ci = i & 63;
    int rest = i >> 6;
    int co = rest % kCG; rest /= kCG;
    int k = rest % kPKp;
    int g = rest / kPKp;
    float v = 0.f;
    if (ci < 48 && k < kPK) v = pw[((g * kCG + co) * 48 + ci) * kPK + k];
    opos[i] = f2bf(v);
  } else if (bid < 57943){
    const int i = (bid - 53944) * 256 + tid;   // < 1023744
    int r = i >> 7, j = i & 127;
    int b = r / kT1, t = r % kT1;
    float v = 0.f;
    if (j < 120){ int k = j / 40, f = j % 40; v = feats[((size_t)b * kTraw + 2 * t + k) * kF + f]; }
    ocol[i] = f2bf(v);
  } else {
    const int i = (bid - 57943) * 256 + tid;   // < 75264
    int t = kT + i % (kTP - kT);
    int r = i / (kTP - kT);
    vT[(size_t)r * kTP + t] = 0;
  }
}

__global__ void im2col2_k(const unsigned short* __restrict__ act1, unsigned short* __restrict__ out){
  int i = blockIdx.x * 256 + threadIdx.x;
  int n4 = kM * 192;
  if (i >= n4) return;
  int r = i / 192, u = i % 192;
  int b = r / kT, t = r % kT;
  int j = u * 8;
  int k = j >> 9, c = j & 511;
  *(int4*)(out + (size_t)r * 1536 + j) =
      *(const int4*)(act1 + ((size_t)(b * kT1 + 2 * t + k)) * 512 + c);
}

// ---------------- BK=32 GEMM (256 thr): 3-buffer rotation, counted vmcnt, opt split-K ----------------
// PART=1: bf16 partials to Cbf + z*Mm*Nn (bias/res applied in combine kernel).
template<int BM, int GELU, int BF16OUT, int F32OUT, int RES, int PERM, int VOUT, int PART>
__global__ __launch_bounds__(256, (BM == 64) ? 4 : 3) void gemm_k(
    const unsigned short* __restrict__ A, const unsigned short* __restrict__ Bw,
    const float* __restrict__ bias, float* Cf, unsigned short* Cbf,
    const float* res, unsigned short* vT, int Mtiles, int Ntiles, int Mm, int Nn, int Kk, int ldk)
{
  constexpr int MW = BM / 32;
  constexpr int LPT = (BM == 64) ? 3 : 4;
  __shared__ unsigned short smem[3 * (BM + 128) * 32];
  unsigned short* lsA0 = smem;
  unsigned short* lsB0 = smem + 3 * BM * 32;
  const int tid = threadIdx.x;
  const int lane = tid & 63, w = tid >> 6;
  const int wm = w >> 1, wn = w & 1;
  const int lo = lane & 15, hi = lane >> 4;
  const int NK = Kk >> 5;
  const int zc = blockIdx.z;
  A += (size_t)zc * Kk;
  Bw += (size_t)zc * Kk;

  int tm, tn;
  xcd_map(blockIdx.x, Mtiles, Ntiles, tm, tn);

  auto stage = [&](int buf, int kt){
    #pragma unroll
    for (int p = 0; p < BM / 64; ++p){
      int row = p * 64 + (tid >> 2);
      int ga = min(tm * BM + row, Mm - 1);
      int sl = (tid & 3) ^ ((row >> 1) & 3);
      gl2lds16(A + (size_t)ga * ldk + kt * 32 + sl * 8, lsA0 + buf * BM * 32 + (p * 64 + w * 16) * 32);
    }
    #pragma unroll
    for (int p = 0; p < 2; ++p){
      int row = p * 64 + (tid >> 2);
      int gb = min(tn * 128 + row, Nn - 1);
      int sl = (tid & 3) ^ ((row >> 1) & 3);
      gl2lds16(Bw + (size_t)gb * ldk + kt * 32 + sl * 8, lsB0 + buf * 128 * 32 + (p * 64 + w * 16) * 32);
    }
  };

  f32x4 acc[MW][4];
  #pragma unroll
  for (int m = 0; m < MW; m++)
    #pragma unroll
    for (int n = 0; n < 4; n++) acc[m][n] = f32x4{0.f, 0.f, 0.f, 0.f};

  stage(0, 0);
  stage(1, 1);

  for (int kt = 0; kt < NK; ++kt){
    if (kt + 1 < NK){
      if (LPT == 3) asm volatile("s_waitcnt vmcnt(3)" ::: "memory");
      else          asm volatile("s_waitcnt vmcnt(4)" ::: "memory");
    } else {
      asm volatile("s_waitcnt vmcnt(0)" ::: "memory");
    }
    asm volatile("s_barrier" ::: "memory");
    const unsigned short* As = lsA0 + (kt % 3) * BM * 32;
    const unsigned short* Bs = lsB0 + (kt % 3) * 128 * 32;
    short8 af[MW], bfv[4];
    #pragma unroll
    for (int m = 0; m < MW; m++){
      int row = wm * (16 * MW) + m * 16 + lo;
      int sp = hi ^ ((row >> 1) & 3);
      af[m] = *(const short8*)&As[row * 32 + sp * 8];
    }
    #pragma unroll
    for (int n = 0; n < 4; n++){
      int row = wn * 64 + n * 16 + lo;
      int sp = hi ^ ((row >> 1) & 3);
      bfv[n] = *(const short8*)&Bs[row * 32 + sp * 8];
    }
    if (kt + 2 < NK) stage((kt + 2) % 3, kt + 2);
    __builtin_amdgcn_s_setprio(1);
    #pragma unroll
    for (int m = 0; m < MW; m++)
      #pragma unroll
      for (int n = 0; n < 4; n++)
        acc[m][n] = __builtin_amdgcn_mfma_f32_16x16x32_bf16(af[m], bfv[n], acc[m][n], 0, 0, 0);
    __builtin_amdgcn_s_setprio(0);
  }

  __syncthreads();
  float* esm = (float*)smem + w * (16 * 68);
  const size_t zoff = (size_t)zc * Mm * Nn;
  #pragma unroll
  for (int m = 0; m < MW; m++){
    #pragma unroll
    for (int n = 0; n < 4; n++)
      #pragma unroll
      for (int r = 0; r < 4; r++)
        esm[(hi * 4 + r) * 68 + n * 16 + lo] = acc[m][n][r];
    #pragma unroll
    for (int rr = 0; rr < 4; rr++){
      const int lr = rr * 4 + hi;
      const int lc = lo * 4;
      float4 v = *(float4*)&esm[lr * 68 + lc];
      const int row = tm * BM + wm * (16 * MW) + m * 16 + lr;
      const int col = tn * 128 + wn * 64 + lc;
      if (row < Mm && col < Nn){
        if (PART){
          ushort4v u; u.x = f2bf(v.x); u.y = f2bf(v.y); u.z = f2bf(v.z); u.w = f2bf(v.w);
          *(ushort4v*)&Cbf[zoff + (size_t)row * Nn + col] = u;
        } else {
          float4 b4 = *(const float4*)&bias[col];
          float o0 = v.x + b4.x, o1 = v.y + b4.y, o2 = v.z + b4.z, o3 = v.w + b4.w;
          if (GELU){ o0 = gelu_f(o0); o1 = gelu_f(o1); o2 = gelu_f(o2); o3 = gelu_f(o3); }
          if (RES){
            float4 r4 = *(const float4*)&res[(size_t)row * Nn + col];
            o0 += r4.x; o1 += r4.y; o2 += r4.z; o3 += r4.w;
          }
          if (F32OUT){
            int orow = PERM ? ((row % kT) * kB + row / kT) : row;
            float4 u; u.x = o0; u.y = o1; u.z = o2; u.w = o3;
            *(float4*)&Cf[(size_t)orow * Nn + col] = u;
          }
          if (BF16OUT){
            if (!VOUT || col < 1536){  // V-columns only live in vT
              ushort4v u; u.x = f2bf(o0); u.y = f2bf(o1); u.z = f2bf(o2); u.w = f2bf(o3);
              *(ushort4v*)&Cbf[(size_t)row * Nn + col] = u;
            }
          }
          if (VOUT && col >= 1536){
            int bb = row / kT, tt = row % kT;
            float ov[4] = {o0, o1, o2, o3};
            #pragma unroll
            for (int j = 0; j < 4; j++){
              int cj = col + j;
              int hh = (cj - 1536) >> 6, dd = (cj - 1536) & 63;
              vT[(((size_t)(bb * kH + hh)) * kDH + dd) * kTP + tt] = f2bf(ov[j]);
            }
          }
        }
      }
    }
  }
}

// ---------------- BK=32 GEMM (512 thr, BM=128 x BN=256) — proj ----------------
template<int GELU, int BF16OUT, int F32OUT, int RES, int PERM, int VOUT>
__global__ __launch_bounds__(512, 2) void gemm512_k(
    const unsigned short* __restrict__ A, const unsigned short* __restrict__ Bw,
    const float* __restrict__ bias, float* Cf, unsigned short* Cbf,
    const float* res, unsigned short* vT, int Mtiles, int Ntiles, int Mm, int Nn, int Kk)
{
  __shared__ unsigned short smem[3 * (128 + 256) * 32];
  unsigned short* lsA0 = smem;
  unsigned short* lsB0 = smem + 3 * 128 * 32;
  const int tid = threadIdx.x;
  const int lane = tid & 63, w = tid >> 6;
  const int wm = w >> 2, wn = w & 3;
  const int lo = lane & 15, hi = lane >> 4;
  const int NK = Kk >> 5;

  int tm, tn;
  xcd_map(blockIdx.x, Mtiles, Ntiles, tm, tn);

  auto stage = [&](int buf, int kt){
    {
      int row = tid >> 2;
      int ga = min(tm * 128 + row, Mm - 1);
      int sl = (tid & 3) ^ ((row >> 1) & 3);
      gl2lds16(A + (size_t)ga * Kk + kt * 32 + sl * 8, lsA0 + buf * 128 * 32 + (w * 16) * 32);
    }
    #pragma unroll
    for (int p = 0; p < 2; ++p){
      int row = p * 128 + (tid >> 2);
      int gb = min(tn * 256 + row, Nn - 1);
      int sl = (tid & 3) ^ ((row >> 1) & 3);
      gl2lds16(Bw + (size_t)gb * Kk + kt * 32 + sl * 8, lsB0 + buf * 256 * 32 + (p * 128 + w * 16) * 32);
    }
  };

  f32x4 acc[4][4];
  #pragma unroll
  for (int m = 0; m < 4; m++)
    #pragma unroll
    for (int n = 0; n < 4; n++) acc[m][n] = f32x4{0.f, 0.f, 0.f, 0.f};

  stage(0, 0);
  stage(1, 1);

  for (int kt = 0; kt < NK; ++kt){
    if (kt + 1 < NK) asm volatile("s_waitcnt vmcnt(3)" ::: "memory");
    else             asm volatile("s_waitcnt vmcnt(0)" ::: "memory");
    asm volatile("s_barrier" ::: "memory");
    const unsigned short* As = lsA0 + (kt % 3) * 128 * 32;
    const unsigned short* Bs = lsB0 + (kt % 3) * 256 * 32;
    short8 af[4], bfv[4];
    #pragma unroll
    for (int m = 0; m < 4; m++){
      int row = wm * 64 + m * 16 + lo;
      int sp = hi ^ ((row >> 1) & 3);
      af[m] = *(const short8*)&As[row * 32 + sp * 8];
    }
    #pragma unroll
    for (int n = 0; n < 4; n++){
      int row = wn * 64 + n * 16 + lo;
      int sp = hi ^ ((row >> 1) & 3);
      bfv[n] = *(const short8*)&Bs[row * 32 + sp * 8];
    }
    if (kt + 2 < NK) stage((kt + 2) % 3, kt + 2);
    __builtin_amdgcn_s_setprio(1);
    #pragma unroll
    for (int m = 0; m < 4; m++)
      #pragma unroll
      for (int n = 0; n < 4; n++)
        acc[m][n] = __builtin_amdgcn_mfma_f32_16x16x32_bf16(af[m], bfv[n], acc[m][n], 0, 0, 0);
    __builtin_amdgcn_s_setprio(0);
  }

  __syncthreads();
  float* esm = (float*)smem + w * (16 * 68);
  #pragma unroll
  for (int m = 0; m < 4; m++){
    #pragma unroll
    for (int n = 0; n < 4; n++)
      #pragma unroll
      for (int r = 0; r < 4; r++)
        esm[(hi * 4 + r) * 68 + n * 16 + lo] = acc[m][n][r];
    #pragma unroll
    for (int rr = 0; rr < 4; rr++){
      const int lr = rr * 4 + hi;
      const int lc = lo * 4;
      float4 v = *(float4*)&esm[lr * 68 + lc];
      const int row = tm * 128 + wm * 64 + m * 16 + lr;
      const int col = tn * 256 + wn * 64 + lc;
      if (row < Mm && col < Nn){
        float4 b4 = *(const float4*)&bias[col];
        float o0 = v.x + b4.x, o1 = v.y + b4.y, o2 = v.z + b4.z, o3 = v.w + b4.w;
        if (GELU){ o0 = gelu_f(o0); o1 = gelu_f(o1); o2 = gelu_f(o2); o3 = gelu_f(o3); }
        if (RES){
          float4 r4 = *(const float4*)&res[(size_t)row * Nn + col];
          o0 += r4.x; o1 += r4.y; o2 += r4.z; o3 += r4.w;
        }
        if (F32OUT){
          int orow = PERM ? ((row % kT) * kB + row / kT) : row;
          float4 u; u.x = o0; u.y = o1; u.z = o2; u.w = o3;
          *(float4*)&Cf[(size_t)orow * Nn + col] = u;
        }
        if (BF16OUT){
          ushort4v u; u.x = f2bf(o0); u.y = f2bf(o1); u.z = f2bf(o2); u.w = f2bf(o3);
          *(ushort4v*)&Cbf[(size_t)row * Nn + col] = u;
        }
      }
    }
  }
}

// ---------------- LayerNorm over D=768, 4 rows per 256-thread block ----------------
template<int OUTBF>
__global__ __launch_bounds__(256) void ln_k(const float* __restrict__ x, const float* __restrict__ gg,
    const float* __restrict__ bb, float* __restrict__ of, unsigned short* __restrict__ ob)
{
  const int row = blockIdx.x * 4 + (threadIdx.x >> 6);
  if (row >= kM) return;
  const int lane = threadIdx.x & 63;
  const float* xr = x + (size_t)row * kD;
  float4 v0 = *(const float4*)(xr + lane * 4);
  float4 v1 = *(const float4*)(xr + 256 + lane * 4);
  float4 v2 = *(const float4*)(xr + 512 + lane * 4);
  float s = v0.x + v0.y + v0.z + v0.w + v1.x + v1.y + v1.z + v1.w + v2.x + v2.y + v2.z + v2.w;
  #pragma unroll
  for (int o = 32; o >= 1; o >>= 1) s += __shfl_xor(s, o);
  const float mean = s * (1.0f / 768.0f);
  float q = 0.f;
  {
    float dx, dy, dz, dw;
    dx = v0.x - mean; dy = v0.y - mean; dz = v0.z - mean; dw = v0.w - mean; q += dx*dx + dy*dy + dz*dz + dw*dw;
    dx = v1.x - mean; dy = v1.y - mean; dz = v1.z - mean; dw = v1.w - mean; q += dx*dx + dy*dy + dz*dz + dw*dw;
    dx = v2.x - mean; dy = v2.y - mean; dz = v2.z - mean; dw = v2.w - mean; q += dx*dx + dy*dy + dz*dz + dw*dw;
  }
  #pragma unroll
  for (int o = 32; o >= 1; o >>= 1) q += __shfl_xor(q, o);
  const float rstd = rsqrtf(q * (1.0f / 768.0f) + 1e-5f);
  #pragma unroll
  for (int j = 0; j < 3; j++){
    float4 v = (j == 0) ? v0 : ((j == 1) ? v1 : v2);
    int c0 = j * 256 + lane * 4;
    float4 g4 = *(const float4*)(gg + c0);
    float4 b4 = *(const float4*)(bb + c0);
    float o0 = (v.x - mean) * rstd * g4.x + b4.x;
    float o1 = (v.y - mean) * rstd * g4.y + b4.y;
    float o2 = (v.z - mean) * rstd * g4.z + b4.z;
    float o3 = (v.w - mean) * rstd * g4.w + b4.w;
    if (OUTBF){
      ushort4v u; u.x = f2bf(o0); u.y = f2bf(o1); u.z = f2bf(o2); u.w = f2bf(o3);
      *(ushort4v*)(ob + (size_t)row * kD + c0) = u;
    } else {
      float4 u; u.x = o0; u.y = o1; u.z = o2; u.w = o3;
      *(float4*)(of + (size_t)row * kD + c0) = u;
    }
  }
}

// ---------------- fused double LayerNorm: y = LN(x; g0,b0) -> xo (f32); LN(y; g1,b1) -> hb (bf16) ----------------
__global__ __launch_bounds__(256) void lnln_k(const float* __restrict__ x,
    const float* __restrict__ g0v, const float* __restrict__ b0v,
    const float* __restrict__ g1v, const float* __restrict__ b1v,
    float* __restrict__ xo, unsigned short* __restrict__ hb)
{
  const int row = blockIdx.x * 4 + (threadIdx.x >> 6);
  if (row >= kM) return;
  const int lane = threadIdx.x & 63;
  const float* xr = x + (size_t)row * kD;
  float y[12];
  {
    float4 v0 = *(const float4*)(xr + lane * 4);
    float4 v1 = *(const float4*)(xr + 256 + lane * 4);
    float4 v2 = *(const float4*)(xr + 512 + lane * 4);
    float s = v0.x + v0.y + v0.z + v0.w + v1.x + v1.y + v1.z + v1.w + v2.x + v2.y + v2.z + v2.w;
    #pragma unroll
    for (int o = 32; o >= 1; o >>= 1) s += __shfl_xor(s, o);
    const float mean = s * (1.0f / 768.0f);
    float q = 0.f;
    float xv[12] = {v0.x, v0.y, v0.z, v0.w, v1.x, v1.y, v1.z, v1.w, v2.x, v2.y, v2.z, v2.w};
    #pragma unroll
    for (int t = 0; t < 12; t++){ float d = xv[t] - mean; q += d * d; }
    #pragma unroll
    for (int o = 32; o >= 1; o >>= 1) q += __shfl_xor(q, o);
    const float rstd = rsqrtf(q * (1.0f / 768.0f) + 1e-5f);
    #pragma unroll
    for (int j = 0; j < 3; j++){
      const int c0 = j * 256 + lane * 4;
      float4 g4 = *(const float4*)(g0v + c0);
      float4 b4 = *(const float4*)(b0v + c0);
      y[j*4+0] = (xv[j*4+0] - mean) * rstd * g4.x + b4.x;
      y[j*4+1] = (xv[j*4+1] - mean) * rstd * g4.y + b4.y;
      y[j*4+2] = (xv[j*4+2] - mean) * rstd * g4.z + b4.z;
      y[j*4+3] = (xv[j*4+3] - mean) * rstd * g4.w + b4.w;
      float4 u; u.x = y[j*4+0]; u.y = y[j*4+1]; u.z = y[j*4+2]; u.w = y[j*4+3];
      *(float4*)(xo + (size_t)row * kD + c0) = u;
    }
  }
  {
    float s = 0.f;
    #pragma unroll
    for (int t = 0; t < 12; t++) s += y[t];
    #pragma unroll
    for (int o = 32; o >= 1; o >>= 1) s += __shfl_xor(s, o);
    const float mean = s * (1.0f / 768.0f);
    float q = 0.f;
    #pragma unroll
    for (int t = 0; t < 12; t++){ float d = y[t] - mean; q += d * d; }
    #pragma unroll
    for (int o = 32; o >= 1; o >>= 1) q += __shfl_xor(q, o);
    const float rstd = rsqrtf(q * (1.0f / 768.0f) + 1e-5f);
    #pragma unroll
    for (int j = 0; j < 3; j++){
      const int c0 = j * 256 + lane * 4;
      float4 g4 = *(const float4*)(g1v + c0);
      float4 b4 = *(const float4*)(b1v + c0);
      ushort4v u;
      u.x = f2bf((y[j*4+0] - mean) * rstd * g4.x + b4.x);
      u.y = f2bf((y[j*4+1] - mean) * rstd * g4.y + b4.y);
      u.z = f2bf((y[j*4+2] - mean) * rstd * g4.z + b4.z);
      u.w = f2bf((y[j*4+3] - mean) * rstd * g4.w + b4.w);
      *(ushort4v*)(hb + (size_t)row * kD + c0) = u;
    }
  }
}

// ---------------- combine 2 bf16 W2 partials + bias + residual -> x; then LN (or bf16 cast) ----------------
template<int LNOUT, int WRITEX>
__global__ __launch_bounds__(256) void cmbln_k(const unsigned short* __restrict__ p0,
    const unsigned short* __restrict__ p1,
    const float* __restrict__ bias, float* __restrict__ x, const float* __restrict__ gg,
    const float* __restrict__ bb, unsigned short* __restrict__ ob)
{
  const int row = blockIdx.x * 4 + (threadIdx.x >> 6);
  if (row >= kM) return;
  const int lane = threadIdx.x & 63;
  const size_t base = (size_t)row * kD;
  float xn[12];
  #pragma unroll
  for (int j = 0; j < 3; j++){
    const int c0 = j * 256 + lane * 4;
    float4 xv = *(const float4*)&x[base + c0];
    ushort4v a = *(const ushort4v*)&p0[base + c0];
    ushort4v bv = *(const ushort4v*)&p1[base + c0];
    float4 bs = *(const float4*)&bias[c0];
    xn[j*4+0] = xv.x + bf2f(a.x) + bf2f(bv.x) + bs.x;
    xn[j*4+1] = xv.y + bf2f(a.y) + bf2f(bv.y) + bs.y;
    xn[j*4+2] = xv.z + bf2f(a.z) + bf2f(bv.z) + bs.z;
    xn[j*4+3] = xv.w + bf2f(a.w) + bf2f(bv.w) + bs.w;
    if (WRITEX){
      float4 u; u.x = xn[j*4+0]; u.y = xn[j*4+1]; u.z = xn[j*4+2]; u.w = xn[j*4+3];
      *(float4*)&x[base + c0] = u;
    }
  }
  if (LNOUT){
    float s = 0.f;
    #pragma unroll
    for (int t = 0; t < 12; t++) s += xn[t];
    #pragma unroll
    for (int o = 32; o >= 1; o >>= 1) s += __shfl_xor(s, o);
    const float mean = s * (1.0f / 768.0f);
    float q = 0.f;
    #pragma unroll
    for (int t = 0; t < 12; t++){ float d = xn[t] - mean; q += d * d; }
    #pragma unroll
    for (int o = 32; o >= 1; o >>= 1) q += __shfl_xor(q, o);
    const float rstd = rsqrtf(q * (1.0f / 768.0f) + 1e-5f);
    #pragma unroll
    for (int j = 0; j < 3; j++){
      const int c0 = j * 256 + lane * 4;
      float4 g4 = *(const float4*)(gg + c0);
      float4 b4 = *(const float4*)(bb + c0);
      ushort4v u;
      u.x = f2bf((xn[j*4+0] - mean) * rstd * g4.x + b4.x);
      u.y = f2bf((xn[j*4+1] - mean) * rstd * g4.y + b4.y);
      u.z = f2bf((xn[j*4+2] - mean) * rstd * g4.z + b4.z);
      u.w = f2bf((xn[j*4+3] - mean) * rstd * g4.w + b4.w);
      *(ushort4v*)(ob + base + c0) = u;
    }
  } else {
    #pragma unroll
    for (int j = 0; j < 3; j++){
      const int c0 = j * 256 + lane * 4;
      ushort4v u;
      u.x = f2bf(xn[j*4+0]); u.y = f2bf(xn[j*4+1]);
      u.z = f2bf(xn[j*4+2]); u.w = f2bf(xn[j*4+3]);
      *(ushort4v*)(ob + base + c0) = u;
    }
  }
}

// ---------------- grouped positional conv (K=95, SAME) via MFMA, LDS weights ----------------
__global__ __launch_bounds__(256) void posconv_k(const float* __restrict__ x0,
    const unsigned short* __restrict__ wp, const float* __restrict__ pb, float* __restrict__ xsum)
{
  __shared__ unsigned short xs[224 * 64];
  __shared__ unsigned short wl[2][2 * 48 * 64];
  const int tid = threadIdx.x, lane = tid & 63, w = tid >> 6;
  const int t0 = blockIdx.x * 128, g = blockIdx.y, b = blockIdx.z;
  const int cg0 = g * kCG;
  for (int e = tid; e < 224 * 64; e += 256){
    int tr = e >> 6, ci = e & 63;
    int t = t0 - 47 + tr;
    unsigned short val = 0;
    if (ci < 48 && t >= 0 && t < kT) val = f2bf(x0[((size_t)(b * kT + t)) * kD + cg0 + ci]);
    xs[(tr * 8 + ((ci >> 3) ^ (tr & 7))) * 8 + (ci & 7)] = val;
  }
  const unsigned short* wg = wp + (size_t)g * kPKp * kCG * 64;
  auto stageW = [&](int buf, int c){
    const unsigned short* src = wg + (size_t)c * 2 * kCG * 64;
    #pragma unroll
    for (int j = 0; j < 3; j++){
      int row = w * 24 + j * 8 + (lane >> 3);
      int slot = (lane & 7) ^ (row & 7);
      gl2lds16(src + (size_t)row * 64 + slot * 8, &wl[buf][(w * 24 + j * 8) * 64]);
    }
  };
  stageW(0, 0);

  f32x4 acc[2][3];
  #pragma unroll
  for (int rg = 0; rg < 2; rg++)
    #pragma unroll
    for (int f = 0; f < 3; f++) acc[rg][f] = f32x4{0.f, 0.f, 0.f, 0.f};

  const int lo = lane & 15, hi = lane >> 4;
  for (int c = 0; c < 48; ++c){
    __syncthreads();
    if (c + 1 < 48) stageW((c + 1) & 1, c + 1);
    const int buf = c & 1;
    #pragma unroll
    for (int kk = 0; kk < 2; kk++){
      const int k = c * 2 + kk;
      short8 a0[2], a1[2];
      #pragma unroll
      for (int rg = 0; rg < 2; rg++){
        const int row0 = w * 32 + rg * 16 + lo + k;
        a0[rg] = *(const short8*)&xs[(row0 * 8 + ((hi    ) ^ (row0 & 7))) * 8];
        a1[rg] = *(const short8*)&xs[(row0 * 8 + ((hi + 4) ^ (row0 & 7))) * 8];
      }
      #pragma unroll
      for (int f = 0; f < 3; f++){
        const int wr = kk * 48 + f * 16 + lo;
        short8 b0 = *(const short8*)&wl[buf][(wr * 8 + ((hi    ) ^ (wr & 7))) * 8];
        short8 b1 = *(const short8*)&wl[buf][(wr * 8 + ((hi + 4) ^ (wr & 7))) * 8];
        #pragma unroll
        for (int rg = 0; rg < 2; rg++){
          acc[rg][f] = __builtin_amdgcn_mfma_f32_16x16x32_bf16(a0[rg], b0, acc[rg][f], 0, 0, 0);
          acc[rg][f] = __builtin_amdgcn_mfma_f32_16x16x32_bf16(a1[rg], b1, acc[rg][f], 0, 0, 0);
        }
      }
    }
  }
  #pragma unroll
  for (int rg = 0; rg < 2; rg++){
    #pragma unroll
    for (int f = 0; f < 3; f++){
      #pragma unroll
      for (int r = 0; r < 4; r++){
        int t = t0 + w * 32 + rg * 16 + (hi << 2) + r;
        int co = f * 16 + lo;
        if (t < kT){
          size_t idx = ((size_t)(b * kT + t)) * kD + cg0 + co;
          xsum[idx] = x0[idx] + gelu_f(acc[rg][f][r] + pb[cg0 + co]);
        }
      }
    }
  }
}

// ---------------- split-K flash attention: bf16 chunk partials (additive, fixed-max) ----------------
// (original, best-measured version)
__global__ __launch_bounds__(256) void attn_k(const unsigned short* __restrict__ qkv,
    const unsigned short* __restrict__ vT, unsigned short* __restrict__ pO, float* __restrict__ plsum,
    const float* __restrict__ alibi_scale)
{
  const int tid = threadIdx.x, lane = tid & 63, w = tid >> 6;
  const int qb = blockIdx.x;
  const int cx = blockIdx.y / kH, h = blockIdx.y % kH;
  const int b = blockIdx.z;
  const float slope = exp2f(-8.0f * (float)(h + 1) * (1.0f / 12.0f)) * fmaxf(alibi_scale[h], 0.f);
  const float c1 = 0.125f * 1.44269504f;
  const float sl2 = slope * 1.44269504f;
  const float M2 = 12.0f * 1.44269504f;

  int ktlo, kthi;
  {
    float Wf = (slope > 1e-8f) ? kWIN / slope : 2048.0f;
    int W = (int)fminf(Wf, 2048.0f);
    int jlo = max(0, qb * 128 - W);
    int jhi = min(kT - 1, qb * 128 + 127 + W);
    ktlo = jlo >> 6; kthi = jhi >> 6;
  }
  ktlo = max(ktlo, cx * 8);
  kthi = min(kthi, cx * 8 + 7);
  if (ktlo > kthi) return;

  __shared__ unsigned short Kl[2][64 * 64];
  __shared__ unsigned short Vl[2][64 * 64];
  __shared__ unsigned short Pl[4][32 * 72];
  const int q0 = qb * 128 + w * 32;
  const int lo = lane & 15, hi = lane >> 4;

  short8 aq[2][2];
  #pragma unroll
  for (int qa = 0; qa < 2; qa++){
    const int qr = min(q0 + qa * 16 + lo, kT - 1);
    const unsigned short* qbase = qkv + ((size_t)(b * kT + qr)) * 2304 + h * 64 + hi * 8;
    aq[qa][0] = *(const short8*)(qbase);
    aq[qa][1] = *(const short8*)(qbase + 32);
  }

  f32x4 oacc[2][4];
  #pragma unroll
  for (int qa = 0; qa < 2; qa++)
    #pragma unroll
    for (int f = 0; f < 4; f++) oacc[qa][f] = f32x4{0.f, 0.f, 0.f, 0.f};
  float lrow[2][4];
  #pragma unroll
  for (int qa = 0; qa < 2; qa++)
    #pragma unroll
    for (int r = 0; r < 4; r++) lrow[qa][r] = 0.f;

  const unsigned short* kbase = qkv + (size_t)b * kT * 2304 + 768 + h * 64;
  const unsigned short* vbase = vT + ((size_t)(b * kH + h)) * kDH * kTP;
  unsigned short* pl = &Pl[w][0];

  auto stageKV = [&](int buf, int kt){
    const int j0 = kt * 64;
    #pragma unroll
    for (int c = 0; c < 2; c++){
      int row = w * 16 + c * 8 + (lane >> 3);
      int slot = (lane & 7) ^ (row & 7);
      int kr = min(j0 + row, kT - 1);
      gl2lds16(kbase + (size_t)kr * 2304 + slot * 8, &Kl[buf][(w * 16 + c * 8) * 64]);
      gl2lds16(vbase + (size_t)row * kTP + j0 + slot * 8, &Vl[buf][(w * 16 + c * 8) * 64]);
    }
  };
  stageKV(ktlo & 1, ktlo);

  for (int kt = ktlo; kt <= kthi; ++kt){
    __syncthreads();
    if (kt + 1 <= kthi) stageKV((kt + 1) & 1, kt + 1);
    const int buf = kt & 1;
    const int j0 = kt * 64;
    f32x4 sac[2][4];
    __builtin_amdgcn_s_setprio(1);
    #pragma unroll
    for (int f = 0; f < 4; f++){
      const int krow = f * 16 + lo;
      short8 b0 = *(const short8*)&Kl[buf][(krow * 8 + ((hi    ) ^ (krow & 7))) * 8];
      short8 b1 = *(const short8*)&Kl[buf][(krow * 8 + ((hi + 4) ^ (krow & 7))) * 8];
      #pragma unroll
      for (int qa = 0; qa < 2; qa++){
        f32x4 s = f32x4{0.f, 0.f, 0.f, 0.f};
        s = __builtin_amdgcn_mfma_f32_16x16x32_bf16(aq[qa][0], b0, s, 0, 0, 0);
        s = __builtin_amdgcn_mfma_f32_16x16x32_bf16(aq[qa][1], b1, s, 0, 0, 0);
        sac[qa][f] = s;
      }
    }
    __builtin_amdgcn_s_setprio(0);
    #pragma unroll
    for (int qa = 0; qa < 2; qa++){
      #pragma unroll
      for (int f = 0; f < 4; f++){
        const int j = j0 + f * 16 + lo;
        const float jf = (float)j;
        #pragma unroll
        for (int r = 0; r < 4; r++){
          const float qrow = (float)(q0 + qa * 16 + hi * 4 + r);
          float sv = sac[qa][f][r] * c1 - fabsf(qrow - jf) * sl2 - M2;
          if (j >= kT) sv = -1.0e30f;
          float e = exp2f(sv);
          lrow[qa][r] += e;
          pl[(qa * 16 + hi * 4 + r) * 72 + f * 16 + lo] = f2bf(e);
        }
      }
    }
    __builtin_amdgcn_s_setprio(1);
    #pragma unroll
    for (int c2 = 0; c2 < 2; c2++){
      short8 pa[2];
      #pragma unroll
      for (int qa = 0; qa < 2; qa++)
        pa[qa] = *(const short8*)&pl[(qa * 16 + lo) * 72 + c2 * 32 + hi * 8];
      #pragma unroll
      for (int f = 0; f < 4; f++){
        const int dr = f * 16 + lo;
        short8 bv = *(const short8*)&Vl[buf][(dr * 8 + ((c2 * 4 + hi) ^ (dr & 7))) * 8];
        #pragma unroll
        for (int qa = 0; qa < 2; qa++)
          oacc[qa][f] = __builtin_amdgcn_mfma_f32_16x16x32_bf16(pa[qa], bv, oacc[qa][f], 0, 0, 0);
      }
    }
    __builtin_amdgcn_s_setprio(0);
  }
  const int pidx = (cx * kB + b) * kH + h;
  unsigned short* po = pO + (size_t)pidx * kTP * 64;
  #pragma unroll
  for (int o = 1; o < 16; o <<= 1){
    #pragma unroll
    for (int qa = 0; qa < 2; qa++)
      #pragma unroll
      for (int r = 0; r < 4; r++) lrow[qa][r] += __shfl_xor(lrow[qa][r], o);
  }
  #pragma unroll
  for (int qa = 0; qa < 2; qa++){
    #pragma unroll
    for (int f = 0; f < 4; f++){
      #pragma unroll
      for (int r = 0; r < 4; r++){
        int q = q0 + qa * 16 + hi * 4 + r;
        if (q < kT) po[(size_t)q * 64 + f * 16 + lo] = f2bf(oacc[qa][f][r]);
      }
    }
  }
  if (lo == 0){
    #pragma unroll
    for (int qa = 0; qa < 2; qa++)
      #pragma unroll
      for (int r = 0; r < 4; r++){
        int q = q0 + qa * 16 + hi * 4 + r;
        if (q < kT) plsum[(size_t)pidx * kTP + q] = lrow[qa][r];
      }
  }
}

// ---------------- attention chunk-combine + normalize -> bf16 O ----------------
__global__ __launch_bounds__(256) void attnred_k(const unsigned short* __restrict__ pO,
    const float* __restrict__ plsum, const float* __restrict__ alibi_scale,
    unsigned short* __restrict__ obf)
{
  int i = blockIdx.x * 256 + threadIdx.x;
  const int total = kB * kH * kT * 16;
  if (i >= total) return;
  const int d4 = i & 15;
  int rest = i >> 4;
  const int q = rest % kT; rest /= kT;
  const int h = rest % kH;
  const int b = rest / kH;
  const float slope = exp2f(-8.0f * (float)(h + 1) * (1.0f / 12.0f)) * fmaxf(alibi_scale[h], 0.f);
  int ktlo, kthi;
  {
    float Wf = (slope > 1e-8f) ? kWIN / slope : 2048.0f;
    int W = (int)fminf(Wf, 2048.0f);
    const int qb = q >> 7;
    int jlo = max(0, qb * 128 - W);
    int jhi = min(kT - 1, qb * 128 + 127 + W);
    ktlo = jlo >> 6; kthi = jhi >> 6;
  }
  float a0 = 0.f, a1 = 0.f, a2 = 0.f, a3 = 0.f;
  float l = 0.f;
  #pragma unroll
  for (int c = 0; c < kNCH; c++){
    if (c * 8 + 7 >= ktlo && c * 8 <= kthi){
      const int pidx = (c * kB + b) * kH + h;
      ushort4v v = *(const ushort4v*)&pO[((size_t)pidx * kTP + q) * 64 + d4 * 4];
      a0 += bf2f(v.x); a1 += bf2f(v.y); a2 += bf2f(v.z); a3 += bf2f(v.w);
      l += plsum[(size_t)pidx * kTP + q];
    }
  }
  const float inv = 1.0f / l;
  ushort4v u;
  u.x = f2bf(a0 * inv); u.y = f2bf(a1 * inv);
  u.z = f2bf(a2 * inv); u.w = f2bf(a3 * inv);
  *(ushort4v*)&obf[((size_t)(b * kT + q)) * kD + h * 64 + d4 * 4] = u;
}

} // namespace

extern "C" void kernel_launch(void* const* d_in, const int* in_sizes, int n_in,
                              void* d_out, int out_size, void* d_ws, size_t ws_size,
                              hipStream_t stream)
{
  (void)in_sizes; (void)n_in; (void)out_size; (void)ws_size;
  const float* feats   = (const float*)d_in[0];
  const float* conv1_w = (const float*)d_in[1];
  const float* conv1_b = (const float*)d_in[2];
  const float* conv2_w = (const float*)d_in[3];
  const float* conv2_b = (const float*)d_in[4];
  const float* fln_g   = (const float*)d_in[5];
  const float* fln_b   = (const float*)d_in[6];
  const float* pos_w   = (const float*)d_in[7];
  const float* pos_b   = (const float*)d_in[8];
  const float* cln_g   = (const float*)d_in[9];
  const float* cln_b   = (const float*)d_in[10];
  const float* alibi   = (const float*)d_in[11];
  const float* Wqkv    = (const float*)d_in[12];
  const float* bqkv    = (const float*)d_in[13];
  const float* Wo      = (const float*)d_in[14];
  const float* bo      = (const float*)d_in[15];
  const float* ln1g    = (const float*)d_in[16];
  const float* ln1b    = (const float*)d_in[17];
  const float* ln2g    = (const float*)d_in[18];
  const float* ln2b    = (const float*)d_in[19];
  const float* W1      = (const float*)d_in[20];
  const float* b1      = (const float*)d_in[21];
  const float* W2      = (const float*)d_in[22];
  const float* b2      = (const float*)d_in[23];
  const float* projw   = (const float*)d_in[24];
  const float* projb   = (const float*)d_in[25];
  float* out = (float*)d_out;

  char* wsp = (char*)d_ws;
  size_t off = 0;
  auto alloc = [&](size_t nbytes)->char*{
    char* p = wsp + off;
    off += (nbytes + 255) & ~(size_t)255;
    return p;
  };
  // NOTE: the 5 bf16 weight buffers below are contiguous (all sizes % 256B == 0);
  // the prologue cast segment writes them as one region starting at wqkv_bf.
  unsigned short* wqkv_bf  = (unsigned short*)alloc((size_t)kL * 2304 * 768 * 2);
  unsigned short* wo_bf    = (unsigned short*)alloc((size_t)kL * 768 * 768 * 2);
  unsigned short* w1_bf    = (unsigned short*)alloc((size_t)kL * 3072 * 768 * 2);
  unsigned short* w2_bf    = (unsigned short*)alloc((size_t)kL * 768 * 3072 * 2);
  unsigned short* wproj_bf = (unsigned short*)alloc((size_t)kV * 768 * 2);
  unsigned short* wc1      = (unsigned short*)alloc((size_t)kC1 * 128 * 2);
  unsigned short* wc2      = (unsigned short*)alloc((size_t)kD * 1536 * 2);
  unsigned short* wpos     = (unsigned short*)alloc((size_t)kPG * kPKp * kCG * 64 * 2);
  // conv/prologue scratch — dead during the layer loop; attn/W2 partials alias this region
  char* pbase = wsp + off;
  unsigned short* a1col    = (unsigned short*)alloc((size_t)kM1 * 128 * 2);
  unsigned short* act1     = (unsigned short*)alloc((size_t)kM1 * 512 * 2);
  unsigned short* a2col    = (unsigned short*)alloc((size_t)kM * 1536 * 2);
  float* xa    = (float*)alloc((size_t)kM * 768 * 4);
  float* x0    = (float*)alloc((size_t)kM * 768 * 4);
  float* xsum  = (float*)alloc((size_t)kM * 768 * 4);
  float* x     = (float*)alloc((size_t)kM * 768 * 4);
  unsigned short* h_bf   = (unsigned short*)alloc((size_t)kM * 768 * 2);
  unsigned short* qkv_bf = (unsigned short*)alloc((size_t)kM * 2304 * 2);
  unsigned short* vTb    = (unsigned short*)alloc((size_t)kB * kH * kDH * kTP * 2);
  unsigned short* o_bf   = (unsigned short*)alloc((size_t)kM * 768 * 2);
  unsigned short* f_bf   = (unsigned short*)alloc((size_t)kM * 3072 * 2);
  unsigned short* xf_bf  = (unsigned short*)alloc((size_t)kM * 768 * 2);
  // aliases over dead prologue region: attn partials (26 MB) then W2 bf16 partials (12.3 MB)
  unsigned short* pO = (unsigned short*)pbase;
  float* plsum = (float*)(pbase + (size_t)kNCH * kB * kH * kTP * 64 * 2);
  unsigned short* pG = (unsigned short*)(pbase + (size_t)kNCH * kB * kH * kTP * 64 * 2
                                               + (size_t)kNCH * kB * kH * kTP * 4);
  unsigned short* pG1 = pG + (size_t)kM * 768;

  auto cgrid = [](size_t n){ return dim3((unsigned)((n + 255) / 256)); };

  // fused prologue: all weight casts/packs + im2col1 + vT zero-fill in ONE dispatch
  prologue_k<<<dim3(58237), 256, 0, stream>>>(Wqkv, Wo, W1, W2, projw, wqkv_bf,
      conv1_w, wc1, conv2_w, wc2, pos_w, wpos, feats, a1col, vTb);

  // conv1 (GEMM, K padded to 128) -> act1 bf16 with GELU
  gemm_k<128,1,1,0,0,0,0,0><<<dim3(63 * 4), 256, 0, stream>>>(a1col, wc1, conv1_b, nullptr, act1, nullptr, nullptr, 63, 4, kM1, 512, 128, 128);
  im2col2_k<<<cgrid((size_t)kM * 192), 256, 0, stream>>>(act1, a2col);
  // conv2 -> xa f32 with GELU
  gemm_k<64,1,0,1,0,0,0,0><<<dim3(63 * 6), 256, 0, stream>>>(a2col, wc2, conv2_b, xa, nullptr, nullptr, nullptr, 63, 6, kM, 768, 1536, 1536);
  ln_k<0><<<dim3(1000), 256, 0, stream>>>(xa, fln_g, fln_b, x0, nullptr);
  posconv_k<<<dim3(16, 16, 2), 256, 0, stream>>>(x0, wpos, pos_b, xsum);
  // fused: x = LN(xsum; ctx_ln), h_bf = LN(x; ln1[0])
  lnln_k<<<dim3(1000), 256, 0, stream>>>(xsum, cln_g, cln_b, ln1g, ln1b, x, h_bf);

  const int nred = kB * kH * kT * 16;
  for (int i = 0; i < kL; i++){
    // qkv GEMM with fused V-transpose epilogue (V cols only to vT)
    gemm_k<128,0,1,0,0,0,1,0><<<dim3(32 * 18), 256, 0, stream>>>(h_bf, wqkv_bf + (size_t)i * 2304 * 768,
        bqkv + i * 2304, nullptr, qkv_bf, nullptr, vTb, 32, 18, kM, 2304, 768, 768);
    attn_k<<<dim3(16, kH * kNCH, 2), 256, 0, stream>>>(qkv_bf, vTb, pO, plsum, alibi);
    attnred_k<<<cgrid(nred), 256, 0, stream>>>(pO, plsum, alibi, o_bf);
    gemm_k<64,0,0,1,1,0,0,0><<<dim3(63 * 6), 256, 0, stream>>>(o_bf, wo_bf + (size_t)i * 768 * 768,
        bo + i * 768, x, nullptr, x, nullptr, 63, 6, kM, 768, 768, 768);
    ln_k<1><<<dim3(1000), 256, 0, stream>>>(x, ln2g + i * 768, ln2b + i * 768, nullptr, h_bf);
    // W1 GEMM with GELU
    gemm_k<128,1,1,0,0,0,0,0><<<dim3(32 * 24), 256, 0, stream>>>(h_bf, w1_bf + (size_t)i * 3072 * 768,
        b1 + i * 3072, nullptr, f_bf, nullptr, nullptr, 32, 24, kM, 3072, 768, 768);
    // W2 split-K (2 x 1536) -> bf16 partials; combine + residual + next LN (or bf16 cast) fused
    gemm_k<64,0,0,0,0,0,0,1><<<dim3(63 * 6, 1, 2), 256, 0, stream>>>(f_bf, w2_bf + (size_t)i * 768 * 3072,
        nullptr, nullptr, pG, nullptr, nullptr, 63, 6, kM, 768, 1536, 3072);
    if (i < kL - 1){
      cmbln_k<1,1><<<dim3(1000), 256, 0, stream>>>(pG, pG1, b2 + i * 768, x,
          ln1g + (i + 1) * 768, ln1b + (i + 1) * 768, h_bf);
    } else {
      cmbln_k<0,0><<<dim3(1000), 256, 0, stream>>>(pG, pG1, b2 + i * 768, x,
          nullptr, nullptr, xf_bf);
    }
  }
  // final projection (512-thr, BM=128 x BN=256, 1024 blocks) with [t, b, v] output permutation
  gemm512_k<0,0,1,0,1,0><<<dim3(32 * 32), 512, 0, stream>>>(xf_bf, wproj_bf, projb, out, nullptr, nullptr, nullptr, 32, 32, kM, kV, 768);
}